// Round 10
// baseline (187.335 us; speedup 1.0000x reference)
//
#include <hip/hip_runtime.h>
#include <cstdint>
#include <cstddef>

// CausalSelfAttention MI355X (gfx950). fp32 I/O, bf16 MFMA compute, fp32 accum.
// B=2, T=2048, C=1024, H=16, Dh=64.
// [cast f32->bf16 + device rope-table] -> [QKV gemm: 256x256 8-phase template,
// fused rmsnorm+rope epilogue; q pre-scaled by 0.125*log2(e)] -> [flash
// attention: KEY-SPLIT waves (round-8 verified internals) + SPLIT-K work
// decomposition: qt<=15 = one block, qt>=16 = two ~equal key chunks ->
// 48 uniform items/bh (max 16 steps), 1536 blocks, 4 resident/CU. Linear
// softmax (no running max) => partial (o,l) add; split chunks write fp32
// partials to d_out scratch] -> [attn_reduce: sum 2 partials -> y] ->
// [gemm proj (m97)].
// Lessons: never dyn-index reg arrays; never global-gather K/V fragments;
// balance by ADDING parallel blocks (split-K), not serializing tiles (r9).

typedef short bf16x8 __attribute__((ext_vector_type(8)));
typedef short bf16x4 __attribute__((ext_vector_type(4)));
typedef float floatx4 __attribute__((ext_vector_type(4)));
typedef float floatx2 __attribute__((ext_vector_type(2)));
typedef unsigned short ushortx8 __attribute__((ext_vector_type(8)));
typedef unsigned short ushortx4 __attribute__((ext_vector_type(4)));
typedef unsigned int uintx2 __attribute__((ext_vector_type(2)));

#define DEVI __device__ __forceinline__

DEVI unsigned short f2bf(float f) {
    unsigned int u = __builtin_bit_cast(unsigned int, f);
    u += 0x7fffu + ((u >> 16) & 1u);   // RNE; finite values only
    return (unsigned short)(u >> 16);
}
// pack 2 fp32 -> 2 bf16 in one dword: low16=bf(a), high16=bf(b) (inputs >= 0)
DEVI unsigned int pkbf2(float a, float b) {
    unsigned int ua = __builtin_bit_cast(unsigned int, a) + 0x8000u;
    unsigned int ub = __builtin_bit_cast(unsigned int, b) + 0x8000u;
    return __builtin_amdgcn_perm(ub, ua, 0x07060302);
}

// async global->LDS, 16B per lane; LDS dest = wave-uniform base + lane*16.
DEVI void glds16(const unsigned short* g, unsigned short* l) {
    __builtin_amdgcn_global_load_lds(
        (const __attribute__((address_space(1))) unsigned int*)g,
        (__attribute__((address_space(3))) unsigned int*)l, 16, 0, 0);
}

DEVI void cast8(unsigned short* dst, const float* src) {
    floatx4 a = *(const floatx4*)src;
    floatx4 b = *(const floatx4*)(src + 4);
    ushortx8 o;
    o[0] = f2bf(a[0]); o[1] = f2bf(a[1]); o[2] = f2bf(a[2]); o[3] = f2bf(a[3]);
    o[4] = f2bf(b[0]); o[5] = f2bf(b[1]); o[6] = f2bf(b[2]); o[7] = f2bf(b[3]);
    *(ushortx8*)dst = o;
}

// ---------------------------------------------------------------------------
__global__ __launch_bounds__(256)
void cast_inputs(const float* __restrict__ x, const float* __restrict__ wa,
                 const float* __restrict__ wp,
                 unsigned short* __restrict__ xb, unsigned short* __restrict__ wab,
                 unsigned short* __restrict__ wpb, float* __restrict__ ropetab)
{
    size_t g = (size_t)blockIdx.x * 256 + threadIdx.x;
    size_t stride = (size_t)gridDim.x * 256;
    for (size_t i = g; i < (4194304 / 8); i += stride) cast8(xb  + i * 8, x  + i * 8);
    for (size_t i = g; i < (3145728 / 8); i += stride) cast8(wab + i * 8, wa + i * 8);
    for (size_t i = g; i < (1048576 / 8); i += stride) cast8(wpb + i * 8, wp + i * 8);
    // rope table: [t=0..2047][f=0..31] -> (cos, sin) of t * 1e4^(-f/32).
    for (size_t i = g; i < 65536; i += stride) {
        int t = (int)(i >> 5), f = (int)(i & 31);
        float ang = (float)t * __expf(-(float)f * 0.28782313662425572f); // ln(1e4)/32
        float sn, cs;
        __sincosf(ang, &sn, &cs);
        ropetab[2 * i]     = cs;
        ropetab[2 * i + 1] = sn;
    }
}

// ---------------------------------------------------------------------------
// QKV GEMM, 8-phase 256^2 template. C[M=4096,N=3072] = A[M,1024] @ B[N,1024]^T.
// ---------------------------------------------------------------------------
__global__ __launch_bounds__(512, 2)
void gemm_qkv_8ph(const unsigned short* __restrict__ A,
                  const unsigned short* __restrict__ B,
                  const float* __restrict__ ropetab,
                  unsigned short* __restrict__ Cqk,
                  unsigned short* __restrict__ Vt)
{
    __shared__ __align__(16) unsigned short lds[2][2][256 * 64]; // [buf][A/B][..] 128KiB

    const int tid  = threadIdx.x;
    const int lane = tid & 63;
    const int w    = tid >> 6;         // 0..7
    const int wm   = w >> 2;           // 0..1 (output row half)
    const int wn   = w & 3;            // 0..3 (output col quarter = one head)
    const int quad = lane >> 4;
    const int lm   = lane & 15;

    // bijective XCD swizzle (192 blocks, 192 % 8 == 0)
    const int lin = blockIdx.y * 12 + blockIdx.x;
    const int s   = (lin & 7) * 24 + (lin >> 3);
    const int m0  = (s / 12) * 256;
    const int n0  = (s % 12) * 256;

    const int srow = tid >> 3;                                       // 0..63
    const int scol = (((tid & 7) ^ ((tid >> 3) & 7)) * 8);           // pre-swizzled
    const int ldst = w * 512;                                        // wave LDS base

#define STG_A(u, WBi, kq) glds16(&A[(size_t)(m0 + (u) * 64 + srow) * 1024 + (kq) + scol], \
                                 &lds[WBi][0][(u) * 4096 + ldst])
#define STG_B(u, WBi, kq) glds16(&B[(size_t)(n0 + (u) * 64 + srow) * 1024 + (kq) + scol], \
                                 &lds[WBi][1][(u) * 4096 + ldst])
#define RD_A(RBi, rrow, kk) (*(const bf16x8*)&lds[RBi][0][(rrow) * 64 + ((((kk) * 4 + quad) ^ ((rrow) & 7)) * 8)])
#define RD_B(RBi, rrow, kk) (*(const bf16x8*)&lds[RBi][1][(rrow) * 64 + ((((kk) * 4 + quad) ^ ((rrow) & 7)) * 8)])

    floatx4 acc[8][4] = {};
    bf16x8 afr[4][2];
    bf16x8 bfr[4][2];

#define MQ(MB, JB)                                                              \
  do {                                                                          \
    _Pragma("unroll")                                                           \
    for (int kk = 0; kk < 2; ++kk)                                              \
      _Pragma("unroll")                                                         \
      for (int mi = 0; mi < 4; ++mi)                                            \
        _Pragma("unroll")                                                       \
        for (int j2 = 0; j2 < 2; ++j2)                                          \
          acc[(MB) + mi][(JB) + j2] = __builtin_amdgcn_mfma_f32_16x16x32_bf16(  \
              afr[mi][kk], bfr[(JB) + j2][kk], acc[(MB) + mi][(JB) + j2], 0, 0, 0); \
  } while (0)

#define TILE(RBi, WBi, KT, LASTF)                                               \
  do {                                                                          \
    const int kn = ((KT) + 1) * 64;                                             \
    if (!(LASTF)) { STG_B(0, WBi, kn); STG_B(1, WBi, kn); }                     \
    _Pragma("unroll")                                                           \
    for (int kk = 0; kk < 2; ++kk) {                                            \
      _Pragma("unroll")                                                         \
      for (int mi = 0; mi < 4; ++mi)                                            \
        afr[mi][kk] = RD_A(RBi, wm * 128 + mi * 16 + lm, kk);                   \
      _Pragma("unroll")                                                         \
      for (int j2 = 0; j2 < 2; ++j2)                                            \
        bfr[j2][kk] = RD_B(RBi, wn * 64 + j2 * 16 + lm, kk);                    \
    }                                                                           \
    asm volatile("s_waitcnt lgkmcnt(8)" ::: "memory");                          \
    __builtin_amdgcn_s_barrier();                                               \
    asm volatile("s_waitcnt lgkmcnt(0)" ::: "memory");                          \
    __builtin_amdgcn_s_setprio(1); MQ(0, 0); __builtin_amdgcn_s_setprio(0);     \
    __builtin_amdgcn_s_barrier();                                               \
    if (!(LASTF)) { STG_B(2, WBi, kn); STG_B(3, WBi, kn); }                     \
    _Pragma("unroll")                                                           \
    for (int kk = 0; kk < 2; ++kk)                                              \
      _Pragma("unroll")                                                         \
      for (int j2 = 0; j2 < 2; ++j2)                                            \
        bfr[2 + j2][kk] = RD_B(RBi, wn * 64 + (2 + j2) * 16 + lm, kk);          \
    if (!(LASTF)) { asm volatile("s_waitcnt vmcnt(4)" ::: "memory"); }          \
    else          { asm volatile("s_waitcnt vmcnt(0)" ::: "memory"); }          \
    __builtin_amdgcn_s_barrier();                                               \
    asm volatile("s_waitcnt lgkmcnt(0)" ::: "memory");                          \
    __builtin_amdgcn_s_setprio(1); MQ(0, 2); __builtin_amdgcn_s_setprio(0);     \
    __builtin_amdgcn_s_barrier();                                               \
    if (!(LASTF)) { STG_A(0, WBi, kn); STG_A(2, WBi, kn); }                     \
    _Pragma("unroll")                                                           \
    for (int kk = 0; kk < 2; ++kk)                                              \
      _Pragma("unroll")                                                         \
      for (int mi = 0; mi < 4; ++mi)                                            \
        afr[mi][kk] = RD_A(RBi, wm * 128 + 64 + mi * 16 + lm, kk);              \
    __builtin_amdgcn_s_barrier();                                               \
    asm volatile("s_waitcnt lgkmcnt(0)" ::: "memory");                          \
    __builtin_amdgcn_s_setprio(1); MQ(4, 2); __builtin_amdgcn_s_setprio(0);     \
    __builtin_amdgcn_s_barrier();                                               \
    if (!(LASTF)) { STG_A(1, WBi, kn); STG_A(3, WBi, kn);                       \
                    asm volatile("s_waitcnt vmcnt(2)" ::: "memory"); }          \
    __builtin_amdgcn_s_barrier();                                               \
    __builtin_amdgcn_s_setprio(1); MQ(4, 0); __builtin_amdgcn_s_setprio(0);     \
    __builtin_amdgcn_s_barrier();                                               \
  } while (0)

    STG_B(0, 0, 0); STG_B(1, 0, 0); STG_B(2, 0, 0); STG_B(3, 0, 0);
    STG_A(0, 0, 0); STG_A(2, 0, 0); STG_A(1, 0, 0); STG_A(3, 0, 0);
    asm volatile("s_waitcnt vmcnt(2)" ::: "memory");
    __builtin_amdgcn_s_barrier();

    for (int kt = 0; kt < 14; kt += 2) {
        TILE(0, 1, kt, false);
        TILE(1, 0, kt + 1, false);
    }
    TILE(0, 1, 14, false);
    TILE(1, 0, 15, true);

    // -------- fused epilogue: RMSNorm + RoPE via precomputed table --------
    // q (cols < 1024) additionally scaled by 0.125*log2(e) so attention can
    // use exp2(S) directly (softmax scale folded into Q).
    const bool is_v = (n0 + wn * 64) >= 2048;   // wave-uniform; one head per wave
    if (!is_v) {
        const float qsc = ((n0 + wn * 64) < 1024) ? 0.18033688011112043f : 1.0f;
        const floatx2* rtab = (const floatx2*)ropetab;
        #pragma unroll
        for (int mi = 0; mi < 8; ++mi) {
            float rn[4];
            #pragma unroll
            for (int r = 0; r < 4; ++r) {
                float ss = 0.0f;
                #pragma unroll
                for (int j = 0; j < 4; ++j) ss += acc[mi][j][r] * acc[mi][j][r];
                ss += __shfl_xor(ss, 1, 64);
                ss += __shfl_xor(ss, 2, 64);
                ss += __shfl_xor(ss, 4, 64);
                ss += __shfl_xor(ss, 8, 64);
                rn[r] = rsqrtf(ss * (1.0f / 64.0f) + 1.1920929e-07f);
            }
            #pragma unroll
            for (int r = 0; r < 4; ++r) {
                int row = m0 + wm * 128 + mi * 16 + quad * 4 + r;
                int t = row & 2047;
                floatx2 cs0 = rtab[t * 32 + lm];        // f = lm      (j=0,2)
                floatx2 cs1 = rtab[t * 32 + 16 + lm];   // f = 16+lm   (j=1,3)
                float g = rn[r];
                #pragma unroll
                for (int j = 0; j < 4; ++j) {
                    int d = j * 16 + lm;
                    float cs = (j & 1) ? cs1[0] : cs0[0];
                    float sn = (j & 1) ? cs1[1] : cs0[1];
                    float v  = acc[mi][j][r] * g;
                    float vp = acc[mi][j ^ 2][r] * g;          // partner d^32
                    float sgn = (d < 32) ? -1.0f : 1.0f;       // (-x2, x1)
                    Cqk[(size_t)row * 2048 + (n0 + wn * 64 + d)] =
                        f2bf((v * cs + sgn * vp * sn) * qsc);
                }
            }
        }
    } else {
        #pragma unroll
        for (int mi = 0; mi < 8; ++mi)
            #pragma unroll
            for (int j = 0; j < 4; ++j) {
                int col  = n0 + wn * 64 + j * 16 + lm;
                int row0 = m0 + wm * 128 + mi * 16 + quad * 4;
                int bq = row0 >> 11, t0 = row0 & 2047;
                ushortx4 pk;
                #pragma unroll
                for (int r = 0; r < 4; ++r) pk[r] = f2bf(acc[mi][j][r]);
                *(ushortx4*)&Vt[((size_t)(bq * 1024 + (col - 2048))) * 2048 + t0] = pk;
            }
    }
#undef TILE
#undef MQ
#undef RD_A
#undef RD_B
#undef STG_A
#undef STG_B
}

// ---------------------------------------------------------------------------
// m97-structure GEMM (proj only). C[M,N] = A[M,K] @ B[N,K]^T.
// ---------------------------------------------------------------------------
template <int BN, int BK>
__global__ __launch_bounds__(256)
void gemm_bt(const unsigned short* __restrict__ A, const unsigned short* __restrict__ B,
             float* __restrict__ Cf, int M, int N, int K)
{
    constexpr int WCOLS = (BN == 128) ? 2 : 1;
    constexpr int WROWS = 4 / WCOLS;
    constexpr int MI    = 128 / (16 * WROWS);
    constexpr int LPR   = BK / 8;
    constexpr int RPI   = 64 / LPR;

    __shared__ __align__(16) unsigned short As[128 * BK];
    __shared__ __align__(16) unsigned short Bs[BN * BK];

    const int tid  = threadIdx.x;
    const int lane = tid & 63;
    const int w    = tid >> 6;
    const int wm   = w / WCOLS, wn = w % WCOLS;
    const int quad = lane >> 4;
    const int lm   = lane & 15;
    const int m0 = blockIdx.y * 128;
    const int n0 = blockIdx.x * BN;
    const int sr = lane / LPR;
    const int sc = (lane % LPR) * 8;

    floatx4 acc[MI][4] = {};

    for (int k0 = 0; k0 < K; k0 += BK) {
        __syncthreads();
        #pragma unroll
        for (int i = 0; i < 32 / RPI; ++i) {
            int r = w * 32 + i * RPI;
            glds16(&A[(size_t)(m0 + r + sr) * K + k0 + sc], &As[r * BK]);
        }
        #pragma unroll
        for (int i = 0; i < (BN / 4) / RPI; ++i) {
            int r = w * (BN / 4) + i * RPI;
            glds16(&B[(size_t)(n0 + r + sr) * K + k0 + sc], &Bs[r * BK]);
        }
        __syncthreads();

        #pragma unroll
        for (int kk = 0; kk < BK / 32; ++kk) {
            bf16x8 a[MI];
            #pragma unroll
            for (int i = 0; i < MI; ++i)
                a[i] = *(const bf16x8*)&As[(wm * (16 * MI) + i * 16 + lm) * BK + kk * 32 + quad * 8];
            #pragma unroll
            for (int j = 0; j < 4; ++j) {
                bf16x8 b = *(const bf16x8*)&Bs[(wn * 64 + j * 16 + lm) * BK + kk * 32 + quad * 8];
                #pragma unroll
                for (int i = 0; i < MI; ++i)
                    acc[i][j] = __builtin_amdgcn_mfma_f32_16x16x32_bf16(a[i], b, acc[i][j], 0, 0, 0);
            }
        }
    }

    #pragma unroll
    for (int i = 0; i < MI; ++i)
        #pragma unroll
        for (int j = 0; j < 4; ++j) {
            int col  = n0 + wn * 64 + j * 16 + lm;
            int row0 = m0 + wm * (16 * MI) + i * 16 + quad * 4;
            #pragma unroll
            for (int r = 0; r < 4; ++r)
                Cf[(size_t)(row0 + r) * N + col] = acc[i][j][r];
        }
}

// ---------------------------------------------------------------------------
// Flash attention, KEY-SPLIT waves + SPLIT-K decomposition.
// QBLK=64, 256 threads / 4 waves; wave w owns keys w*16..w*16+15 of each
// 64-key tile (2 K-b128 + 4 V-b64 LDS reads per step). Work item
// (blockIdx.y -> g_items): (qt, t0, nt). qt<=15: single chunk, direct y
// write. qt>=16: two chunks; each writes fp32 (o,l) partials (linear
// softmax => partials add). Internals identical to verified round 8.
// ---------------------------------------------------------------------------
#define ENC(qt, t0, nt) ((qt) | ((t0) << 8) | ((nt) << 16))
__constant__ int g_items[48] = {
    ENC(31,0,16), ENC(31,16,16), ENC(30,0,16), ENC(15,0,16),
    ENC(30,16,15), ENC(29,0,15), ENC(29,15,15), ENC(28,0,15), ENC(14,0,15),
    ENC(28,15,14), ENC(27,0,14), ENC(27,14,14), ENC(26,0,14), ENC(13,0,14),
    ENC(26,14,13), ENC(25,0,13), ENC(25,13,13), ENC(24,0,13), ENC(12,0,13),
    ENC(24,13,12), ENC(23,0,12), ENC(23,12,12), ENC(22,0,12), ENC(11,0,12),
    ENC(22,12,11), ENC(21,0,11), ENC(21,11,11), ENC(20,0,11), ENC(10,0,11),
    ENC(20,11,10), ENC(19,0,10), ENC(19,10,10), ENC(18,0,10), ENC(9,0,10),
    ENC(18,10,9),  ENC(17,0,9),  ENC(17,9,9),   ENC(16,0,9),  ENC(8,0,9),
    ENC(16,9,8),   ENC(7,0,8),
    ENC(6,0,7), ENC(5,0,6), ENC(4,0,5), ENC(3,0,4), ENC(2,0,3), ENC(1,0,2),
    ENC(0,0,1)
};

#define GRP(OT, LT, QT, g, KT, DG)                                             \
  {                                                                            \
    floatx4 sa = {};                                                           \
    sa = __builtin_amdgcn_mfma_f32_16x16x32_bf16(kf0, QT[0], sa, 0, 0, 0);     \
    sa = __builtin_amdgcn_mfma_f32_16x16x32_bf16(kf1, QT[1], sa, 0, 0, 0);     \
    float p0 = exp2f(sa[0]);                                                   \
    float p1 = exp2f(sa[1]);                                                   \
    float p2 = exp2f(sa[2]);                                                   \
    float p3 = exp2f(sa[3]);                                                   \
    if (DG) {                                                                  \
      int kb = (KT) * 64 + w * 16 + quad * 4;                                  \
      int qr = q0 + (g) * 16 + lm;                                             \
      if (kb + 0 > qr) p0 = 0.0f;                                              \
      if (kb + 1 > qr) p1 = 0.0f;                                              \
      if (kb + 2 > qr) p2 = 0.0f;                                              \
      if (kb + 3 > qr) p3 = 0.0f;                                              \
    }                                                                          \
    uintx2 pk;                                                                 \
    pk[0] = pkbf2(p0, p1);                                                     \
    pk[1] = pkbf2(p2, p3);                                                     \
    bf16x4 pa = __builtin_bit_cast(bf16x4, pk);                                \
    LT = __builtin_amdgcn_mfma_f32_16x16x16bf16_1k(pa, ones4, LT, 0, 0, 0);    \
    OT[0] = __builtin_amdgcn_mfma_f32_16x16x16bf16_1k(pa, vb0, OT[0], 0, 0, 0);\
    OT[1] = __builtin_amdgcn_mfma_f32_16x16x16bf16_1k(pa, vb1, OT[1], 0, 0, 0);\
    OT[2] = __builtin_amdgcn_mfma_f32_16x16x16bf16_1k(pa, vb2, OT[2], 0, 0, 0);\
    OT[3] = __builtin_amdgcn_mfma_f32_16x16x16bf16_1k(pa, vb3, OT[3], 0, 0, 0);\
  }

#define ATTN_STEP(KS, VS, KSn, VSn, KT, DG, LAST)                              \
  do {                                                                         \
    if (!(LAST)) {                                                             \
      const size_t tn = (size_t)((KT) + 1);                                    \
      glds16(kg + tn * 131072,         (KSn) + w * 512);                       \
      glds16(kg + tn * 131072 + 65536, (KSn) + 2048 + w * 512);                \
      glds16(vg + tn * 64,             (VSn) + w * 512);                       \
      glds16(vg + tn * 64 + 65536,     (VSn) + 2048 + w * 512);                \
    }                                                                          \
    bf16x8 kf0 = *(const bf16x8*)&(KS)[kfo0];                                  \
    bf16x8 kf1 = *(const bf16x8*)&(KS)[kfo1];                                  \
    bf16x4 vb0 = *(const bf16x4*)&(VS)[vbo0];                                  \
    bf16x4 vb1 = *(const bf16x4*)&(VS)[vbo1];                                  \
    bf16x4 vb2 = *(const bf16x4*)&(VS)[vbo2];                                  \
    bf16x4 vb3 = *(const bf16x4*)&(VS)[vbo3];                                  \
    GRP(oA, lA, qfA, 0, KT, DG)                                                \
    GRP(oB, lB, qfB, 1, KT, DG)                                                \
    GRP(oC, lC, qfC, 2, KT, DG)                                                \
    GRP(oD, lD, qfD, 3, KT, DG)                                                \
    if (!(LAST)) __syncthreads();                                              \
  } while (0)

#define OWR1(S, OT, g)                                                         \
  _Pragma("unroll")                                                            \
  for (int jd = 0; jd < 4; ++jd)                                               \
    _Pragma("unroll")                                                          \
    for (int r = 0; r < 4; ++r)                                                \
      (S)[((g) * 16 + quad * 4 + r) * 64 + jd * 16 + lm] = OT[jd][r];
#define OWR(S) { OWR1(S, oA, 0) OWR1(S, oB, 1) OWR1(S, oC, 2) OWR1(S, oD, 3) }
#define OAC1(S, OT, g)                                                         \
  _Pragma("unroll")                                                            \
  for (int jd = 0; jd < 4; ++jd)                                               \
    _Pragma("unroll")                                                          \
    for (int r = 0; r < 4; ++r)                                                \
      OT[jd][r] += (S)[((g) * 16 + quad * 4 + r) * 64 + jd * 16 + lm];
#define OAC(S) { OAC1(S, oA, 0) OAC1(S, oB, 1) OAC1(S, oC, 2) OAC1(S, oD, 3) }

#define YWR(OT, g)                                                             \
  {                                                                            \
    float rv[4];                                                               \
    _Pragma("unroll")                                                          \
    for (int r = 0; r < 4; ++r) {                                              \
      int qi = (g) * 16 + quad * 4 + r;                                        \
      rv[r] = 1.0f / (lsc[qi] + lsc[64 + qi] + lsc[128 + qi] + lsc[192 + qi]); \
    }                                                                          \
    _Pragma("unroll")                                                          \
    for (int jd = 0; jd < 4; ++jd)                                             \
      _Pragma("unroll")                                                        \
      for (int r = 0; r < 4; ++r)                                              \
        Y[((size_t)(b * 2048 + q0 + (g) * 16 + quad * 4 + r)) * 1024 +         \
          h * 64 + jd * 16 + lm] = f2bf(OT[jd][r] * rv[r]);                    \
  }

#define PWR(OT, g)                                                             \
  {                                                                            \
    _Pragma("unroll")                                                          \
    for (int r = 0; r < 4; ++r) {                                              \
      int qi = (g) * 16 + quad * 4 + r;                                        \
      if (lm == 0)                                                             \
        pl[qi] = lsc[qi] + lsc[64 + qi] + lsc[128 + qi] + lsc[192 + qi];       \
      _Pragma("unroll")                                                        \
      for (int jd = 0; jd < 4; ++jd)                                           \
        po[qi * 64 + jd * 16 + lm] = OT[jd][r];                                \
    }                                                                          \
  }

__global__ __launch_bounds__(256, 2)
void attention(const unsigned short* __restrict__ qk,
               const unsigned short* __restrict__ Vt,
               unsigned short* __restrict__ Y,
               float* __restrict__ Po, float* __restrict__ Pl)
{
    // 40 KiB: QPs(8K) | Ks0(8K) | Ks1(8K) | Vs0(8K) | Vs1(8K)
    __shared__ __align__(16) unsigned short smem[20480];
    unsigned short* const QPs = smem;
    unsigned short* const Ks0 = smem + 4096;
    unsigned short* const Ks1 = smem + 8192;
    unsigned short* const Vs0 = smem + 12288;
    unsigned short* const Vs1 = smem + 16384;
    float* const lsc  = (float*)smem;            // reduction: l (1KB, over QPs)
    float* const ScrA = (float*)(smem + 4096);   // reduction: o (16KB, Ks0+Ks1)
    float* const ScrB = (float*)(smem + 12288);  // reduction: o (16KB, Vs0+Vs1)

    const int tid  = threadIdx.x;
    const int lane = tid & 63;
    const int w    = tid >> 6;           // wave = key-slice owner
    const int quad = lane >> 4;
    const int lm   = lane & 15;
    const int sx   = lm & 7;

    const int bh = blockIdx.x;
    const int it = g_items[blockIdx.y];
    const int qt = it & 255;
    const int t0 = (it >> 8) & 255;      // first key-tile of this chunk
    const int nt = it >> 16;             // tiles in this chunk (>= 1)
    const int b  = bh >> 4, h = bh & 15;
    const int q0 = qt * 64;
    const bool mflag   = (t0 + nt - 1) == qt;   // chunk ends at diagonal tile
    const bool partial = qt >= 16;              // 2-way split -> partials

    // fragment read offsets (ushort idx), XOR-swizzled chunks
    const int kfo0 = (w * 16 + lm) * 64 + ((quad)     ^ sx) * 8;
    const int kfo1 = (w * 16 + lm) * 64 + ((4 + quad) ^ sx) * 8;
    const int vch  = (w * 2 + (quad >> 1)) ^ sx;
    const int vbo0 = (0 * 16 + lm) * 64 + vch * 8 + (quad & 1) * 4;
    const int vbo1 = (1 * 16 + lm) * 64 + vch * 8 + (quad & 1) * 4;
    const int vbo2 = (2 * 16 + lm) * 64 + vch * 8 + (quad & 1) * 4;
    const int vbo3 = (3 * 16 + lm) * 64 + vch * 8 + (quad & 1) * 4;

    // staging sources (per-lane, source-col XOR so swizzled reads see orig data)
    const int srow = tid >> 3;           // 0..31 (and +32 for 2nd batch)
    const int scol = ((tid & 7) ^ (srow & 7)) * 8;
    const unsigned short* kg = qk + (size_t)b * 4194304 + 1024 + h * 64
                             + (size_t)srow * 2048 + scol;
    const unsigned short* vg = Vt + (size_t)bh * 131072 + (size_t)srow * 2048 + scol;
    const unsigned short* qg = qk + ((size_t)(b * 2048 + q0 + srow)) * 2048
                             + h * 64 + scol;

    // prologue: stage Q + tile t0 (glds; barrier drains vmcnt)
    glds16(qg,         QPs + w * 512);
    glds16(qg + 65536, QPs + 2048 + w * 512);
    glds16(kg + (size_t)t0 * 131072,         Ks0 + w * 512);
    glds16(kg + (size_t)t0 * 131072 + 65536, Ks0 + 2048 + w * 512);
    glds16(vg + t0 * 64,         Vs0 + w * 512);
    glds16(vg + t0 * 64 + 65536, Vs0 + 2048 + w * 512);
    __syncthreads();

    // all 4 q-group fragments in registers (read once)
    bf16x8 qfA[2], qfB[2], qfC[2], qfD[2];
    #pragma unroll
    for (int kk = 0; kk < 2; ++kk) {
        qfA[kk] = *(const bf16x8*)&QPs[(0 * 16 + lm) * 64 + ((kk * 4 + quad) ^ sx) * 8];
        qfB[kk] = *(const bf16x8*)&QPs[(1 * 16 + lm) * 64 + ((kk * 4 + quad) ^ sx) * 8];
        qfC[kk] = *(const bf16x8*)&QPs[(2 * 16 + lm) * 64 + ((kk * 4 + quad) ^ sx) * 8];
        qfD[kk] = *(const bf16x8*)&QPs[(3 * 16 + lm) * 64 + ((kk * 4 + quad) ^ sx) * 8];
    }

    bf16x4 ones4;
    #pragma unroll
    for (int i = 0; i < 4; ++i) ones4[i] = (short)0x3F80;   // bf16 1.0

    floatx4 oA[4] = {}, oB[4] = {}, oC[4] = {}, oD[4] = {};
    floatx4 lA = {}, lB = {}, lC = {}, lD = {};

    // nt steps; static buffer parity (even ct -> buf0); mask only final tile
    // of a diagonal-ending chunk.
    int ct = 0;
    for (; ct + 2 < nt; ct += 2) {
        ATTN_STEP(Ks0, Vs0, Ks1, Vs1, t0 + ct,     false, false);
        ATTN_STEP(Ks1, Vs1, Ks0, Vs0, t0 + ct + 1, false, false);
    }
    if (ct + 2 == nt) {                  // two remaining (ct even)
        ATTN_STEP(Ks0, Vs0, Ks1, Vs1, t0 + ct,     false, false);
        ATTN_STEP(Ks1, Vs1, Ks0, Vs0, t0 + ct + 1, mflag, true);
    } else {                             // one remaining (ct + 1 == nt)
        ATTN_STEP(Ks0, Vs0, Ks1, Vs1, t0 + ct, mflag, true);
    }

    // ---- cross-wave o/l reduction (once per block) ----
    __syncthreads();                     // all steps done; buffers reusable
    if (lm == 0) {
        #pragma unroll
        for (int r = 0; r < 4; ++r) {
            lsc[w * 64 +  0 + quad * 4 + r] = lA[r];
            lsc[w * 64 + 16 + quad * 4 + r] = lB[r];
            lsc[w * 64 + 32 + quad * 4 + r] = lC[r];
            lsc[w * 64 + 48 + quad * 4 + r] = lD[r];
        }
    }
    if (w == 1) { OWR(ScrA) }
    if (w == 3) { OWR(ScrB) }
    __syncthreads();
    if (w == 0) { OAC(ScrA) }
    if (w == 2) { OAC(ScrB) }
    __syncthreads();
    if (w == 2) { OWR(ScrA) }
    __syncthreads();
    if (w == 0) {
        OAC(ScrA)
        if (!partial) {
            YWR(oA, 0)
            YWR(oB, 1)
            YWR(oC, 2)
            YWR(oD, 3)
        } else {
            const int pidx = (bh * 16 + (qt - 16)) * 2 + (t0 ? 1 : 0);
            float* po = Po + (size_t)pidx * 4096;
            float* pl = Pl + (size_t)pidx * 64;
            PWR(oA, 0)
            PWR(oB, 1)
            PWR(oC, 2)
            PWR(oD, 3)
        }
    }
}

// ---------------------------------------------------------------------------
// Sum the 2 split-K partials for qt>=16 and write y (bf16).
// grid (32 bh, 16 qi); 256 threads: row = tid>>2, 16-col group = (tid&3)*16.
// ---------------------------------------------------------------------------
__global__ __launch_bounds__(256)
void attn_reduce(const float* __restrict__ Po, const float* __restrict__ Pl,
                 unsigned short* __restrict__ Y)
{
    const int bh = blockIdx.x, qi = blockIdx.y;
    const int b = bh >> 4, h = bh & 15;
    const int q0 = (16 + qi) * 64;
    const int tid = threadIdx.x;
    const int row = tid >> 2;
    const int c0  = (tid & 3) * 16;
    const size_t base = ((size_t)(bh * 16 + qi)) * 2;
    const float* po0 = Po + (base + 0) * 4096 + row * 64 + c0;
    const float* po1 = Po + (base + 1) * 4096 + row * 64 + c0;
    const float rinv = 1.0f / (Pl[(base + 0) * 64 + row] + Pl[(base + 1) * 64 + row]);
    unsigned short* yp = Y + ((size_t)(b * 2048 + q0 + row)) * 1024 + h * 64 + c0;
    #pragma unroll
    for (int c = 0; c < 2; ++c) {
        floatx4 a  = *(const floatx4*)(po0 + c * 8);
        floatx4 a2 = *(const floatx4*)(po0 + c * 8 + 4);
        floatx4 e  = *(const floatx4*)(po1 + c * 8);
        floatx4 e2 = *(const floatx4*)(po1 + c * 8 + 4);
        ushortx8 o;
        o[0] = f2bf((a[0]  + e[0])  * rinv);
        o[1] = f2bf((a[1]  + e[1])  * rinv);
        o[2] = f2bf((a[2]  + e[2])  * rinv);
        o[3] = f2bf((a[3]  + e[3])  * rinv);
        o[4] = f2bf((a2[0] + e2[0]) * rinv);
        o[5] = f2bf((a2[1] + e2[1]) * rinv);
        o[6] = f2bf((a2[2] + e2[2]) * rinv);
        o[7] = f2bf((a2[3] + e2[3]) * rinv);
        *(ushortx8*)(yp + c * 8) = o;
    }
}

// ---------------------------------------------------------------------------
extern "C" void kernel_launch(void* const* d_in, const int* in_sizes, int n_in,
                              void* d_out, int out_size, void* d_ws, size_t ws_size,
                              hipStream_t stream)
{
    const float* x      = (const float*)d_in[0];   // [2,2048,1024] fp32
    const float* w_attn = (const float*)d_in[1];   // [3072,1024] fp32
    const float* w_proj = (const float*)d_in[2];   // [1024,1024] fp32
    float* out = (float*)d_out;                    // [2,2048,1024] fp32

    // ws: qk 16.8MB | Vt 8.4MB | y 8.4MB | wpb 2.1MB | Pl 256KB  (~36 MB)
    unsigned short* qkbuf = (unsigned short*)d_ws;
    unsigned short* Vtb   = qkbuf + (size_t)4096 * 2048;
    unsigned short* y     = Vtb   + (size_t)32 * 64 * 2048;
    unsigned short* wpb   = y     + (size_t)4096 * 1024;
    float* Plb            = (float*)(wpb + (size_t)1024 * 1024);
    // d_out doubles as scratch: [cast phase] xb/wab/ropetab; [attn phase] Po.
    // All dead before proj writes out.
    unsigned short* xb  = (unsigned short*)d_out;             // 8.4MB
    unsigned short* wab = xb + (size_t)4096 * 1024;           // 6.3MB
    float* ropetab = (float*)(wab + (size_t)3072 * 1024);     // 512KB
    float* Pob = (float*)d_out;                               // 16.78MB (= out size)

    dim3 blk(256);
    cast_inputs<<<dim3(1024), blk, 0, stream>>>(x, w_attn, w_proj, xb, wab, wpb, ropetab);
    gemm_qkv_8ph<<<dim3(12, 16), dim3(512), 0, stream>>>(xb, wab, ropetab, qkbuf, Vtb);
    attention<<<dim3(32, 48), blk, 0, stream>>>(qkbuf, Vtb, y, Pob, Plb);
    attn_reduce<<<dim3(32, 16), blk, 0, stream>>>(Pob, Plb, y);
    gemm_bt<64, 64>
        <<<dim3(16, 32), blk, 0, stream>>>(y, wpb, out, 4096, 1024, 1024);
}

// Round 11
// 180.360 us; speedup vs baseline: 1.0387x; 1.0387x over previous
//
#include <hip/hip_runtime.h>
#include <cstdint>
#include <cstddef>

// CausalSelfAttention MI355X (gfx950). fp32 I/O, bf16 MFMA compute, fp32 accum.
// B=2, T=2048, C=1024, H=16, Dh=64.
// [cast f32->bf16 + device rope-table] -> [QKV gemm: 256x256 8-phase template,
// fused rmsnorm+rope epilogue; q pre-scaled by 0.125*log2(e)] -> [flash
// attention: KEY-SPLIT waves, KVBLK=128 (two 64-key sub-tiles per step ->
// half the barriers/drains, 8 independent GRP chains per step per wave for
// latency hiding at the measured ~1.25-block/CU residency). Per sub-tile a
// wave reads 2 K-b128 + 4 V-b64 (its 16-key slice); Q in regs; P in-register
// (mfma16 PV); o/l cross-wave LDS reduction once per block; direct Y write.]
// -> [gemm proj (m97)].
// Lessons: never dyn-index reg arrays; never global-gather K/V fragments;
// split-K/pairing don't raise residency (r9/r10) - optimize the per-block
// critical path instead.

typedef short bf16x8 __attribute__((ext_vector_type(8)));
typedef short bf16x4 __attribute__((ext_vector_type(4)));
typedef float floatx4 __attribute__((ext_vector_type(4)));
typedef float floatx2 __attribute__((ext_vector_type(2)));
typedef unsigned short ushortx8 __attribute__((ext_vector_type(8)));
typedef unsigned short ushortx4 __attribute__((ext_vector_type(4)));
typedef unsigned int uintx2 __attribute__((ext_vector_type(2)));

#define DEVI __device__ __forceinline__

DEVI unsigned short f2bf(float f) {
    unsigned int u = __builtin_bit_cast(unsigned int, f);
    u += 0x7fffu + ((u >> 16) & 1u);   // RNE; finite values only
    return (unsigned short)(u >> 16);
}
// pack 2 fp32 -> 2 bf16 in one dword: low16=bf(a), high16=bf(b) (inputs >= 0)
DEVI unsigned int pkbf2(float a, float b) {
    unsigned int ua = __builtin_bit_cast(unsigned int, a) + 0x8000u;
    unsigned int ub = __builtin_bit_cast(unsigned int, b) + 0x8000u;
    return __builtin_amdgcn_perm(ub, ua, 0x07060302);
}

// async global->LDS, 16B per lane; LDS dest = wave-uniform base + lane*16.
DEVI void glds16(const unsigned short* g, unsigned short* l) {
    __builtin_amdgcn_global_load_lds(
        (const __attribute__((address_space(1))) unsigned int*)g,
        (__attribute__((address_space(3))) unsigned int*)l, 16, 0, 0);
}

DEVI void cast8(unsigned short* dst, const float* src) {
    floatx4 a = *(const floatx4*)src;
    floatx4 b = *(const floatx4*)(src + 4);
    ushortx8 o;
    o[0] = f2bf(a[0]); o[1] = f2bf(a[1]); o[2] = f2bf(a[2]); o[3] = f2bf(a[3]);
    o[4] = f2bf(b[0]); o[5] = f2bf(b[1]); o[6] = f2bf(b[2]); o[7] = f2bf(b[3]);
    *(ushortx8*)dst = o;
}

// ---------------------------------------------------------------------------
__global__ __launch_bounds__(256)
void cast_inputs(const float* __restrict__ x, const float* __restrict__ wa,
                 const float* __restrict__ wp,
                 unsigned short* __restrict__ xb, unsigned short* __restrict__ wab,
                 unsigned short* __restrict__ wpb, float* __restrict__ ropetab)
{
    size_t g = (size_t)blockIdx.x * 256 + threadIdx.x;
    size_t stride = (size_t)gridDim.x * 256;
    for (size_t i = g; i < (4194304 / 8); i += stride) cast8(xb  + i * 8, x  + i * 8);
    for (size_t i = g; i < (3145728 / 8); i += stride) cast8(wab + i * 8, wa + i * 8);
    for (size_t i = g; i < (1048576 / 8); i += stride) cast8(wpb + i * 8, wp + i * 8);
    // rope table: [t=0..2047][f=0..31] -> (cos, sin) of t * 1e4^(-f/32).
    for (size_t i = g; i < 65536; i += stride) {
        int t = (int)(i >> 5), f = (int)(i & 31);
        float ang = (float)t * __expf(-(float)f * 0.28782313662425572f); // ln(1e4)/32
        float sn, cs;
        __sincosf(ang, &sn, &cs);
        ropetab[2 * i]     = cs;
        ropetab[2 * i + 1] = sn;
    }
}

// ---------------------------------------------------------------------------
// QKV GEMM, 8-phase 256^2 template. C[M=4096,N=3072] = A[M,1024] @ B[N,1024]^T.
// ---------------------------------------------------------------------------
__global__ __launch_bounds__(512, 2)
void gemm_qkv_8ph(const unsigned short* __restrict__ A,
                  const unsigned short* __restrict__ B,
                  const float* __restrict__ ropetab,
                  unsigned short* __restrict__ Cqk,
                  unsigned short* __restrict__ Vt)
{
    __shared__ __align__(16) unsigned short lds[2][2][256 * 64]; // [buf][A/B][..] 128KiB

    const int tid  = threadIdx.x;
    const int lane = tid & 63;
    const int w    = tid >> 6;         // 0..7
    const int wm   = w >> 2;           // 0..1 (output row half)
    const int wn   = w & 3;            // 0..3 (output col quarter = one head)
    const int quad = lane >> 4;
    const int lm   = lane & 15;

    // bijective XCD swizzle (192 blocks, 192 % 8 == 0)
    const int lin = blockIdx.y * 12 + blockIdx.x;
    const int s   = (lin & 7) * 24 + (lin >> 3);
    const int m0  = (s / 12) * 256;
    const int n0  = (s % 12) * 256;

    const int srow = tid >> 3;                                       // 0..63
    const int scol = (((tid & 7) ^ ((tid >> 3) & 7)) * 8);           // pre-swizzled
    const int ldst = w * 512;                                        // wave LDS base

#define STG_A(u, WBi, kq) glds16(&A[(size_t)(m0 + (u) * 64 + srow) * 1024 + (kq) + scol], \
                                 &lds[WBi][0][(u) * 4096 + ldst])
#define STG_B(u, WBi, kq) glds16(&B[(size_t)(n0 + (u) * 64 + srow) * 1024 + (kq) + scol], \
                                 &lds[WBi][1][(u) * 4096 + ldst])
#define RD_A(RBi, rrow, kk) (*(const bf16x8*)&lds[RBi][0][(rrow) * 64 + ((((kk) * 4 + quad) ^ ((rrow) & 7)) * 8)])
#define RD_B(RBi, rrow, kk) (*(const bf16x8*)&lds[RBi][1][(rrow) * 64 + ((((kk) * 4 + quad) ^ ((rrow) & 7)) * 8)])

    floatx4 acc[8][4] = {};
    bf16x8 afr[4][2];
    bf16x8 bfr[4][2];

#define MQ(MB, JB)                                                              \
  do {                                                                          \
    _Pragma("unroll")                                                           \
    for (int kk = 0; kk < 2; ++kk)                                              \
      _Pragma("unroll")                                                         \
      for (int mi = 0; mi < 4; ++mi)                                            \
        _Pragma("unroll")                                                       \
        for (int j2 = 0; j2 < 2; ++j2)                                          \
          acc[(MB) + mi][(JB) + j2] = __builtin_amdgcn_mfma_f32_16x16x32_bf16(  \
              afr[mi][kk], bfr[(JB) + j2][kk], acc[(MB) + mi][(JB) + j2], 0, 0, 0); \
  } while (0)

#define TILE(RBi, WBi, KT, LASTF)                                               \
  do {                                                                          \
    const int kn = ((KT) + 1) * 64;                                             \
    if (!(LASTF)) { STG_B(0, WBi, kn); STG_B(1, WBi, kn); }                     \
    _Pragma("unroll")                                                           \
    for (int kk = 0; kk < 2; ++kk) {                                            \
      _Pragma("unroll")                                                         \
      for (int mi = 0; mi < 4; ++mi)                                            \
        afr[mi][kk] = RD_A(RBi, wm * 128 + mi * 16 + lm, kk);                   \
      _Pragma("unroll")                                                         \
      for (int j2 = 0; j2 < 2; ++j2)                                            \
        bfr[j2][kk] = RD_B(RBi, wn * 64 + j2 * 16 + lm, kk);                    \
    }                                                                           \
    asm volatile("s_waitcnt lgkmcnt(8)" ::: "memory");                          \
    __builtin_amdgcn_s_barrier();                                               \
    asm volatile("s_waitcnt lgkmcnt(0)" ::: "memory");                          \
    __builtin_amdgcn_s_setprio(1); MQ(0, 0); __builtin_amdgcn_s_setprio(0);     \
    __builtin_amdgcn_s_barrier();                                               \
    if (!(LASTF)) { STG_B(2, WBi, kn); STG_B(3, WBi, kn); }                     \
    _Pragma("unroll")                                                           \
    for (int kk = 0; kk < 2; ++kk)                                              \
      _Pragma("unroll")                                                         \
      for (int j2 = 0; j2 < 2; ++j2)                                            \
        bfr[2 + j2][kk] = RD_B(RBi, wn * 64 + (2 + j2) * 16 + lm, kk);          \
    if (!(LASTF)) { asm volatile("s_waitcnt vmcnt(4)" ::: "memory"); }          \
    else          { asm volatile("s_waitcnt vmcnt(0)" ::: "memory"); }          \
    __builtin_amdgcn_s_barrier();                                               \
    asm volatile("s_waitcnt lgkmcnt(0)" ::: "memory");                          \
    __builtin_amdgcn_s_setprio(1); MQ(0, 2); __builtin_amdgcn_s_setprio(0);     \
    __builtin_amdgcn_s_barrier();                                               \
    if (!(LASTF)) { STG_A(0, WBi, kn); STG_A(2, WBi, kn); }                     \
    _Pragma("unroll")                                                           \
    for (int kk = 0; kk < 2; ++kk)                                              \
      _Pragma("unroll")                                                         \
      for (int mi = 0; mi < 4; ++mi)                                            \
        afr[mi][kk] = RD_A(RBi, wm * 128 + 64 + mi * 16 + lm, kk);              \
    __builtin_amdgcn_s_barrier();                                               \
    asm volatile("s_waitcnt lgkmcnt(0)" ::: "memory");                          \
    __builtin_amdgcn_s_setprio(1); MQ(4, 2); __builtin_amdgcn_s_setprio(0);     \
    __builtin_amdgcn_s_barrier();                                               \
    if (!(LASTF)) { STG_A(1, WBi, kn); STG_A(3, WBi, kn);                       \
                    asm volatile("s_waitcnt vmcnt(2)" ::: "memory"); }          \
    __builtin_amdgcn_s_barrier();                                               \
    __builtin_amdgcn_s_setprio(1); MQ(4, 0); __builtin_amdgcn_s_setprio(0);     \
    __builtin_amdgcn_s_barrier();                                               \
  } while (0)

    STG_B(0, 0, 0); STG_B(1, 0, 0); STG_B(2, 0, 0); STG_B(3, 0, 0);
    STG_A(0, 0, 0); STG_A(2, 0, 0); STG_A(1, 0, 0); STG_A(3, 0, 0);
    asm volatile("s_waitcnt vmcnt(2)" ::: "memory");
    __builtin_amdgcn_s_barrier();

    for (int kt = 0; kt < 14; kt += 2) {
        TILE(0, 1, kt, false);
        TILE(1, 0, kt + 1, false);
    }
    TILE(0, 1, 14, false);
    TILE(1, 0, 15, true);

    // -------- fused epilogue: RMSNorm + RoPE via precomputed table --------
    // q (cols < 1024) additionally scaled by 0.125*log2(e) so attention can
    // use exp2(S) directly (softmax scale folded into Q).
    const bool is_v = (n0 + wn * 64) >= 2048;   // wave-uniform; one head per wave
    if (!is_v) {
        const float qsc = ((n0 + wn * 64) < 1024) ? 0.18033688011112043f : 1.0f;
        const floatx2* rtab = (const floatx2*)ropetab;
        #pragma unroll
        for (int mi = 0; mi < 8; ++mi) {
            float rn[4];
            #pragma unroll
            for (int r = 0; r < 4; ++r) {
                float ss = 0.0f;
                #pragma unroll
                for (int j = 0; j < 4; ++j) ss += acc[mi][j][r] * acc[mi][j][r];
                ss += __shfl_xor(ss, 1, 64);
                ss += __shfl_xor(ss, 2, 64);
                ss += __shfl_xor(ss, 4, 64);
                ss += __shfl_xor(ss, 8, 64);
                rn[r] = rsqrtf(ss * (1.0f / 64.0f) + 1.1920929e-07f);
            }
            #pragma unroll
            for (int r = 0; r < 4; ++r) {
                int row = m0 + wm * 128 + mi * 16 + quad * 4 + r;
                int t = row & 2047;
                floatx2 cs0 = rtab[t * 32 + lm];        // f = lm      (j=0,2)
                floatx2 cs1 = rtab[t * 32 + 16 + lm];   // f = 16+lm   (j=1,3)
                float g = rn[r];
                #pragma unroll
                for (int j = 0; j < 4; ++j) {
                    int d = j * 16 + lm;
                    float cs = (j & 1) ? cs1[0] : cs0[0];
                    float sn = (j & 1) ? cs1[1] : cs0[1];
                    float v  = acc[mi][j][r] * g;
                    float vp = acc[mi][j ^ 2][r] * g;          // partner d^32
                    float sgn = (d < 32) ? -1.0f : 1.0f;       // (-x2, x1)
                    Cqk[(size_t)row * 2048 + (n0 + wn * 64 + d)] =
                        f2bf((v * cs + sgn * vp * sn) * qsc);
                }
            }
        }
    } else {
        #pragma unroll
        for (int mi = 0; mi < 8; ++mi)
            #pragma unroll
            for (int j = 0; j < 4; ++j) {
                int col  = n0 + wn * 64 + j * 16 + lm;
                int row0 = m0 + wm * 128 + mi * 16 + quad * 4;
                int bq = row0 >> 11, t0 = row0 & 2047;
                ushortx4 pk;
                #pragma unroll
                for (int r = 0; r < 4; ++r) pk[r] = f2bf(acc[mi][j][r]);
                *(ushortx4*)&Vt[((size_t)(bq * 1024 + (col - 2048))) * 2048 + t0] = pk;
            }
    }
#undef TILE
#undef MQ
#undef RD_A
#undef RD_B
#undef STG_A
#undef STG_B
}

// ---------------------------------------------------------------------------
// m97-structure GEMM (proj only). C[M,N] = A[M,K] @ B[N,K]^T.
// ---------------------------------------------------------------------------
template <int BN, int BK>
__global__ __launch_bounds__(256)
void gemm_bt(const unsigned short* __restrict__ A, const unsigned short* __restrict__ B,
             float* __restrict__ Cf, int M, int N, int K)
{
    constexpr int WCOLS = (BN == 128) ? 2 : 1;
    constexpr int WROWS = 4 / WCOLS;
    constexpr int MI    = 128 / (16 * WROWS);
    constexpr int LPR   = BK / 8;
    constexpr int RPI   = 64 / LPR;

    __shared__ __align__(16) unsigned short As[128 * BK];
    __shared__ __align__(16) unsigned short Bs[BN * BK];

    const int tid  = threadIdx.x;
    const int lane = tid & 63;
    const int w    = tid >> 6;
    const int wm   = w / WCOLS, wn = w % WCOLS;
    const int quad = lane >> 4;
    const int lm   = lane & 15;
    const int m0 = blockIdx.y * 128;
    const int n0 = blockIdx.x * BN;
    const int sr = lane / LPR;
    const int sc = (lane % LPR) * 8;

    floatx4 acc[MI][4] = {};

    for (int k0 = 0; k0 < K; k0 += BK) {
        __syncthreads();
        #pragma unroll
        for (int i = 0; i < 32 / RPI; ++i) {
            int r = w * 32 + i * RPI;
            glds16(&A[(size_t)(m0 + r + sr) * K + k0 + sc], &As[r * BK]);
        }
        #pragma unroll
        for (int i = 0; i < (BN / 4) / RPI; ++i) {
            int r = w * (BN / 4) + i * RPI;
            glds16(&B[(size_t)(n0 + r + sr) * K + k0 + sc], &Bs[r * BK]);
        }
        __syncthreads();

        #pragma unroll
        for (int kk = 0; kk < BK / 32; ++kk) {
            bf16x8 a[MI];
            #pragma unroll
            for (int i = 0; i < MI; ++i)
                a[i] = *(const bf16x8*)&As[(wm * (16 * MI) + i * 16 + lm) * BK + kk * 32 + quad * 8];
            #pragma unroll
            for (int j = 0; j < 4; ++j) {
                bf16x8 b = *(const bf16x8*)&Bs[(wn * 64 + j * 16 + lm) * BK + kk * 32 + quad * 8];
                #pragma unroll
                for (int i = 0; i < MI; ++i)
                    acc[i][j] = __builtin_amdgcn_mfma_f32_16x16x32_bf16(a[i], b, acc[i][j], 0, 0, 0);
            }
        }
    }

    #pragma unroll
    for (int i = 0; i < MI; ++i)
        #pragma unroll
        for (int j = 0; j < 4; ++j) {
            int col  = n0 + wn * 64 + j * 16 + lm;
            int row0 = m0 + wm * (16 * MI) + i * 16 + quad * 4;
            #pragma unroll
            for (int r = 0; r < 4; ++r)
                Cf[(size_t)(row0 + r) * N + col] = acc[i][j][r];
        }
}

// ---------------------------------------------------------------------------
// Flash attention, KEY-SPLIT waves, KVBLK=128 (two 64-key sub-tiles/step).
// QBLK=64, 256 threads / 4 waves; wave w owns keys w*16..+15 of each 64-key
// sub-tile (2 K-b128 + 4 V-b64 LDS reads per sub-tile). Q in regs; P
// in-register (swapped QK^T D-layout == 16x16x16 A-frag); o = full 64x64
// key-partial per wave; cross-wave LDS tree reduction once per block.
// Only the final 128-tile is masked (kb>qr zeroes the dead upper half for
// even qt). LDS 72KB: Q(8K) + 2 x (K 16K + V 16K) double-buffered.
// ---------------------------------------------------------------------------
#define GRP(OT, LT, QT, g, KB, DG)                                             \
  {                                                                            \
    floatx4 sa = {};                                                           \
    sa = __builtin_amdgcn_mfma_f32_16x16x32_bf16(kf0, QT[0], sa, 0, 0, 0);     \
    sa = __builtin_amdgcn_mfma_f32_16x16x32_bf16(kf1, QT[1], sa, 0, 0, 0);     \
    float p0 = exp2f(sa[0]);                                                   \
    float p1 = exp2f(sa[1]);                                                   \
    float p2 = exp2f(sa[2]);                                                   \
    float p3 = exp2f(sa[3]);                                                   \
    if (DG) {                                                                  \
      int kb = (KB) + w * 16 + quad * 4;                                       \
      int qr = q0 + (g) * 16 + lm;                                             \
      if (kb + 0 > qr) p0 = 0.0f;                                              \
      if (kb + 1 > qr) p1 = 0.0f;                                              \
      if (kb + 2 > qr) p2 = 0.0f;                                              \
      if (kb + 3 > qr) p3 = 0.0f;                                              \
    }                                                                          \
    uintx2 pk;                                                                 \
    pk[0] = pkbf2(p0, p1);                                                     \
    pk[1] = pkbf2(p2, p3);                                                     \
    bf16x4 pa = __builtin_bit_cast(bf16x4, pk);                                \
    LT = __builtin_amdgcn_mfma_f32_16x16x16bf16_1k(pa, ones4, LT, 0, 0, 0);    \
    OT[0] = __builtin_amdgcn_mfma_f32_16x16x16bf16_1k(pa, vb0, OT[0], 0, 0, 0);\
    OT[1] = __builtin_amdgcn_mfma_f32_16x16x16bf16_1k(pa, vb1, OT[1], 0, 0, 0);\
    OT[2] = __builtin_amdgcn_mfma_f32_16x16x16bf16_1k(pa, vb2, OT[2], 0, 0, 0);\
    OT[3] = __builtin_amdgcn_mfma_f32_16x16x16bf16_1k(pa, vb3, OT[3], 0, 0, 0);\
  }

// one 64-key sub-tile (s = 0/1) of the current 128-key tile
#define SLICE(KS, VS, s, KT, DG)                                               \
  {                                                                            \
    bf16x8 kf0 = *(const bf16x8*)&(KS)[(s) * 4096 + kfo0];                     \
    bf16x8 kf1 = *(const bf16x8*)&(KS)[(s) * 4096 + kfo1];                     \
    bf16x4 vb0 = *(const bf16x4*)&(VS)[(s) * 4096 + vbo0];                     \
    bf16x4 vb1 = *(const bf16x4*)&(VS)[(s) * 4096 + vbo1];                     \
    bf16x4 vb2 = *(const bf16x4*)&(VS)[(s) * 4096 + vbo2];                     \
    bf16x4 vb3 = *(const bf16x4*)&(VS)[(s) * 4096 + vbo3];                     \
    GRP(oA, lA, qfA, 0, (KT) * 128 + (s) * 64, DG)                             \
    GRP(oB, lB, qfB, 1, (KT) * 128 + (s) * 64, DG)                             \
    GRP(oC, lC, qfC, 2, (KT) * 128 + (s) * 64, DG)                             \
    GRP(oD, lD, qfD, 3, (KT) * 128 + (s) * 64, DG)                             \
  }

#define ATTN_STEP(KS, VS, KSn, VSn, KT, DG, LAST)                              \
  do {                                                                         \
    if (!(LAST)) {                                                             \
      const size_t tn = (size_t)((KT) + 1) * 2;                                \
      glds16(kg + tn * 131072,               (KSn) + w * 512);                 \
      glds16(kg + tn * 131072 + 65536,       (KSn) + 2048 + w * 512);          \
      glds16(kg + (tn + 1) * 131072,         (KSn) + 4096 + w * 512);          \
      glds16(kg + (tn + 1) * 131072 + 65536, (KSn) + 6144 + w * 512);          \
      glds16(vg + tn * 64,                   (VSn) + w * 512);                 \
      glds16(vg + tn * 64 + 65536,           (VSn) + 2048 + w * 512);          \
      glds16(vg + (tn + 1) * 64,             (VSn) + 4096 + w * 512);          \
      glds16(vg + (tn + 1) * 64 + 65536,     (VSn) + 6144 + w * 512);          \
    }                                                                          \
    SLICE(KS, VS, 0, KT, DG)                                                   \
    SLICE(KS, VS, 1, KT, DG)                                                   \
    if (!(LAST)) __syncthreads();                                              \
  } while (0)

#define OWR1(S, OT, g)                                                         \
  _Pragma("unroll")                                                            \
  for (int jd = 0; jd < 4; ++jd)                                               \
    _Pragma("unroll")                                                          \
    for (int r = 0; r < 4; ++r)                                                \
      (S)[((g) * 16 + quad * 4 + r) * 64 + jd * 16 + lm] = OT[jd][r];
#define OWR(S) { OWR1(S, oA, 0) OWR1(S, oB, 1) OWR1(S, oC, 2) OWR1(S, oD, 3) }
#define OAC1(S, OT, g)                                                         \
  _Pragma("unroll")                                                            \
  for (int jd = 0; jd < 4; ++jd)                                               \
    _Pragma("unroll")                                                          \
    for (int r = 0; r < 4; ++r)                                                \
      OT[jd][r] += (S)[((g) * 16 + quad * 4 + r) * 64 + jd * 16 + lm];
#define OAC(S) { OAC1(S, oA, 0) OAC1(S, oB, 1) OAC1(S, oC, 2) OAC1(S, oD, 3) }

#define YWR(OT, g)                                                             \
  {                                                                            \
    float rv[4];                                                               \
    _Pragma("unroll")                                                          \
    for (int r = 0; r < 4; ++r) {                                              \
      int qi = (g) * 16 + quad * 4 + r;                                        \
      rv[r] = 1.0f / (lsc[qi] + lsc[64 + qi] + lsc[128 + qi] + lsc[192 + qi]); \
    }                                                                          \
    _Pragma("unroll")                                                          \
    for (int jd = 0; jd < 4; ++jd)                                             \
      _Pragma("unroll")                                                        \
      for (int r = 0; r < 4; ++r)                                              \
        Y[((size_t)(b * 2048 + q0 + (g) * 16 + quad * 4 + r)) * 1024 +         \
          h * 64 + jd * 16 + lm] = f2bf(OT[jd][r] * rv[r]);                    \
  }

__global__ __launch_bounds__(256, 2)
void attention(const unsigned short* __restrict__ qk,
               const unsigned short* __restrict__ Vt,
               unsigned short* __restrict__ Y)
{
    // 72 KiB: QPs(8K) | Ks0(16K) | Ks1(16K) | Vs0(16K) | Vs1(16K)
    __shared__ __align__(16) unsigned short smem[36864];
    unsigned short* const QPs = smem;
    unsigned short* const Ks0 = smem + 4096;
    unsigned short* const Ks1 = smem + 12288;
    unsigned short* const Vs0 = smem + 20480;
    unsigned short* const Vs1 = smem + 28672;
    float* const lsc  = (float*)smem;            // reduction: l (1KB, over QPs)
    float* const ScrA = (float*)(smem + 4096);   // reduction: o (16KB, over Ks0)
    float* const ScrB = (float*)(smem + 20480);  // reduction: o (16KB, over Vs0)

    const int tid  = threadIdx.x;
    const int lane = tid & 63;
    const int w    = tid >> 6;           // wave = key-slice owner
    const int quad = lane >> 4;
    const int lm   = lane & 15;
    const int sx   = lm & 7;

    const int bh = blockIdx.x;
    const int qt = 31 - blockIdx.y;      // longest first (64-row q-tile idx)
    const int b  = bh >> 4, h = bh & 15;
    const int q0 = qt * 64;
    const int nt = (qt + 2) >> 1;        // number of 128-key steps (1..16)

    // fragment read offsets (ushort idx), XOR-swizzled chunks
    const int kfo0 = (w * 16 + lm) * 64 + ((quad)     ^ sx) * 8;
    const int kfo1 = (w * 16 + lm) * 64 + ((4 + quad) ^ sx) * 8;
    const int vch  = (w * 2 + (quad >> 1)) ^ sx;
    const int vbo0 = (0 * 16 + lm) * 64 + vch * 8 + (quad & 1) * 4;
    const int vbo1 = (1 * 16 + lm) * 64 + vch * 8 + (quad & 1) * 4;
    const int vbo2 = (2 * 16 + lm) * 64 + vch * 8 + (quad & 1) * 4;
    const int vbo3 = (3 * 16 + lm) * 64 + vch * 8 + (quad & 1) * 4;

    // staging sources (per-lane, source-col XOR so swizzled reads see orig data)
    const int srow = tid >> 3;           // 0..31 (and +32 for 2nd batch)
    const int scol = ((tid & 7) ^ (srow & 7)) * 8;
    const unsigned short* kg = qk + (size_t)b * 4194304 + 1024 + h * 64
                             + (size_t)srow * 2048 + scol;
    const unsigned short* vg = Vt + (size_t)bh * 131072 + (size_t)srow * 2048 + scol;
    const unsigned short* qg = qk + ((size_t)(b * 2048 + q0 + srow)) * 2048
                             + h * 64 + scol;

    // prologue: stage Q + 128-key tile 0 (glds; barrier drains vmcnt)
    glds16(qg,         QPs + w * 512);
    glds16(qg + 65536, QPs + 2048 + w * 512);
    glds16(kg,                  Ks0 + w * 512);
    glds16(kg + 65536,          Ks0 + 2048 + w * 512);
    glds16(kg + 131072,         Ks0 + 4096 + w * 512);
    glds16(kg + 131072 + 65536, Ks0 + 6144 + w * 512);
    glds16(vg,              Vs0 + w * 512);
    glds16(vg + 65536,      Vs0 + 2048 + w * 512);
    glds16(vg + 64,         Vs0 + 4096 + w * 512);
    glds16(vg + 64 + 65536, Vs0 + 6144 + w * 512);
    __syncthreads();

    // all 4 q-group fragments in registers (read once)
    bf16x8 qfA[2], qfB[2], qfC[2], qfD[2];
    #pragma unroll
    for (int kk = 0; kk < 2; ++kk) {
        qfA[kk] = *(const bf16x8*)&QPs[(0 * 16 + lm) * 64 + ((kk * 4 + quad) ^ sx) * 8];
        qfB[kk] = *(const bf16x8*)&QPs[(1 * 16 + lm) * 64 + ((kk * 4 + quad) ^ sx) * 8];
        qfC[kk] = *(const bf16x8*)&QPs[(2 * 16 + lm) * 64 + ((kk * 4 + quad) ^ sx) * 8];
        qfD[kk] = *(const bf16x8*)&QPs[(3 * 16 + lm) * 64 + ((kk * 4 + quad) ^ sx) * 8];
    }

    bf16x4 ones4;
    #pragma unroll
    for (int i = 0; i < 4; ++i) ones4[i] = (short)0x3F80;   // bf16 1.0

    floatx4 oA[4] = {}, oB[4] = {}, oC[4] = {}, oD[4] = {};
    floatx4 lA = {}, lB = {}, lC = {}, lD = {};

    // nt steps of 128 keys; static buffer parity (even ct -> buf0);
    // only the final tile masked (kb>qr also zeroes the dead half, even qt).
    int ct = 0;
    for (; ct + 2 < nt; ct += 2) {
        ATTN_STEP(Ks0, Vs0, Ks1, Vs1, ct,     false, false);
        ATTN_STEP(Ks1, Vs1, Ks0, Vs0, ct + 1, false, false);
    }
    if (ct + 2 == nt) {                  // two remaining (ct even)
        ATTN_STEP(Ks0, Vs0, Ks1, Vs1, ct,     false, false);
        ATTN_STEP(Ks1, Vs1, Ks0, Vs0, ct + 1, true,  true);
    } else {                             // one remaining (ct + 1 == nt)
        ATTN_STEP(Ks0, Vs0, Ks1, Vs1, ct, true, true);
    }

    // ---- cross-wave o/l reduction (once per block) ----
    __syncthreads();                     // all steps done; buffers reusable
    if (lm == 0) {
        #pragma unroll
        for (int r = 0; r < 4; ++r) {
            lsc[w * 64 +  0 + quad * 4 + r] = lA[r];
            lsc[w * 64 + 16 + quad * 4 + r] = lB[r];
            lsc[w * 64 + 32 + quad * 4 + r] = lC[r];
            lsc[w * 64 + 48 + quad * 4 + r] = lD[r];
        }
    }
    if (w == 1) { OWR(ScrA) }
    if (w == 3) { OWR(ScrB) }
    __syncthreads();
    if (w == 0) { OAC(ScrA) }
    if (w == 2) { OAC(ScrB) }
    __syncthreads();
    if (w == 2) { OWR(ScrA) }
    __syncthreads();
    if (w == 0) {
        OAC(ScrA)
        YWR(oA, 0)
        YWR(oB, 1)
        YWR(oC, 2)
        YWR(oD, 3)
    }
}

// ---------------------------------------------------------------------------
extern "C" void kernel_launch(void* const* d_in, const int* in_sizes, int n_in,
                              void* d_out, int out_size, void* d_ws, size_t ws_size,
                              hipStream_t stream)
{
    const float* x      = (const float*)d_in[0];   // [2,2048,1024] fp32
    const float* w_attn = (const float*)d_in[1];   // [3072,1024] fp32
    const float* w_proj = (const float*)d_in[2];   // [1024,1024] fp32
    float* out = (float*)d_out;                    // [2,2048,1024] fp32

    // ws: qk 16.8MB | Vt 8.4MB | y 8.4MB | wpb 2.1MB  (35.7 MB total)
    unsigned short* qkbuf = (unsigned short*)d_ws;
    unsigned short* Vtb   = qkbuf + (size_t)4096 * 2048;
    unsigned short* y     = Vtb   + (size_t)32 * 64 * 2048;
    unsigned short* wpb   = y     + (size_t)4096 * 1024;
    // d_out doubles as pre-cast scratch (dead before proj writes):
    unsigned short* xb  = (unsigned short*)d_out;             // 8.4MB
    unsigned short* wab = xb + (size_t)4096 * 1024;           // 6.3MB
    float* ropetab = (float*)(wab + (size_t)3072 * 1024);     // 512KB

    dim3 blk(256);
    cast_inputs<<<dim3(1024), blk, 0, stream>>>(x, w_attn, w_proj, xb, wab, wpb, ropetab);
    gemm_qkv_8ph<<<dim3(12, 16), dim3(512), 0, stream>>>(xb, wab, ropetab, qkbuf, Vtb);
    attention<<<dim3(32, 32), blk, 0, stream>>>(qkbuf, Vtb, y);
    gemm_bt<64, 64>
        <<<dim3(16, 32), blk, 0, stream>>>(y, wpb, out, 4096, 1024, 1024);
}

// Round 12
// 179.400 us; speedup vs baseline: 1.0442x; 1.0054x over previous
//
#include <hip/hip_runtime.h>
#include <cstdint>
#include <cstddef>

// CausalSelfAttention MI355X (gfx950). fp32 I/O, bf16 MFMA compute, fp32 accum.
// B=2, T=2048, C=1024, H=16, Dh=64.
// [cast f32->bf16 + device rope-table] -> [QKV gemm: 256x256 8-phase template,
// fused rmsnorm+rope epilogue; q pre-scaled by 0.125*log2(e)] -> [flash
// attention: KEY-SPLIT waves (round-8 internals) + PREFETCH DISTANCE 2 with
// COUNTED vmcnt(4) (T3/T4): triple-buffered K/V, each step issues tile t+2's
// glds16, waits only for t+1's (never vmcnt(0) mid-loop), raw s_barrier.
// Removes the per-step exposed memory latency that pinned attention at ~46us
// across 8 structures.] -> [gemm proj (m97)].
// Lessons: never dyn-index reg arrays; never global-gather K/V fragments;
// split-K/pairing don't raise residency; the per-step vmcnt(0) drain was the
// hidden ~1300cyc/step cost.

typedef short bf16x8 __attribute__((ext_vector_type(8)));
typedef short bf16x4 __attribute__((ext_vector_type(4)));
typedef float floatx4 __attribute__((ext_vector_type(4)));
typedef float floatx2 __attribute__((ext_vector_type(2)));
typedef unsigned short ushortx8 __attribute__((ext_vector_type(8)));
typedef unsigned short ushortx4 __attribute__((ext_vector_type(4)));
typedef unsigned int uintx2 __attribute__((ext_vector_type(2)));

#define DEVI __device__ __forceinline__

DEVI unsigned short f2bf(float f) {
    unsigned int u = __builtin_bit_cast(unsigned int, f);
    u += 0x7fffu + ((u >> 16) & 1u);   // RNE; finite values only
    return (unsigned short)(u >> 16);
}
// pack 2 fp32 -> 2 bf16 in one dword: low16=bf(a), high16=bf(b) (inputs >= 0)
DEVI unsigned int pkbf2(float a, float b) {
    unsigned int ua = __builtin_bit_cast(unsigned int, a) + 0x8000u;
    unsigned int ub = __builtin_bit_cast(unsigned int, b) + 0x8000u;
    return __builtin_amdgcn_perm(ub, ua, 0x07060302);
}

// async global->LDS, 16B per lane; LDS dest = wave-uniform base + lane*16.
DEVI void glds16(const unsigned short* g, unsigned short* l) {
    __builtin_amdgcn_global_load_lds(
        (const __attribute__((address_space(1))) unsigned int*)g,
        (__attribute__((address_space(3))) unsigned int*)l, 16, 0, 0);
}

DEVI void cast8(unsigned short* dst, const float* src) {
    floatx4 a = *(const floatx4*)src;
    floatx4 b = *(const floatx4*)(src + 4);
    ushortx8 o;
    o[0] = f2bf(a[0]); o[1] = f2bf(a[1]); o[2] = f2bf(a[2]); o[3] = f2bf(a[3]);
    o[4] = f2bf(b[0]); o[5] = f2bf(b[1]); o[6] = f2bf(b[2]); o[7] = f2bf(b[3]);
    *(ushortx8*)dst = o;
}

// ---------------------------------------------------------------------------
__global__ __launch_bounds__(256)
void cast_inputs(const float* __restrict__ x, const float* __restrict__ wa,
                 const float* __restrict__ wp,
                 unsigned short* __restrict__ xb, unsigned short* __restrict__ wab,
                 unsigned short* __restrict__ wpb, float* __restrict__ ropetab)
{
    size_t g = (size_t)blockIdx.x * 256 + threadIdx.x;
    size_t stride = (size_t)gridDim.x * 256;
    for (size_t i = g; i < (4194304 / 8); i += stride) cast8(xb  + i * 8, x  + i * 8);
    for (size_t i = g; i < (3145728 / 8); i += stride) cast8(wab + i * 8, wa + i * 8);
    for (size_t i = g; i < (1048576 / 8); i += stride) cast8(wpb + i * 8, wp + i * 8);
    // rope table: [t=0..2047][f=0..31] -> (cos, sin) of t * 1e4^(-f/32).
    for (size_t i = g; i < 65536; i += stride) {
        int t = (int)(i >> 5), f = (int)(i & 31);
        float ang = (float)t * __expf(-(float)f * 0.28782313662425572f); // ln(1e4)/32
        float sn, cs;
        __sincosf(ang, &sn, &cs);
        ropetab[2 * i]     = cs;
        ropetab[2 * i + 1] = sn;
    }
}

// ---------------------------------------------------------------------------
// QKV GEMM, 8-phase 256^2 template. C[M=4096,N=3072] = A[M,1024] @ B[N,1024]^T.
// ---------------------------------------------------------------------------
__global__ __launch_bounds__(512, 2)
void gemm_qkv_8ph(const unsigned short* __restrict__ A,
                  const unsigned short* __restrict__ B,
                  const float* __restrict__ ropetab,
                  unsigned short* __restrict__ Cqk,
                  unsigned short* __restrict__ Vt)
{
    __shared__ __align__(16) unsigned short lds[2][2][256 * 64]; // [buf][A/B][..] 128KiB

    const int tid  = threadIdx.x;
    const int lane = tid & 63;
    const int w    = tid >> 6;         // 0..7
    const int wm   = w >> 2;           // 0..1 (output row half)
    const int wn   = w & 3;            // 0..3 (output col quarter = one head)
    const int quad = lane >> 4;
    const int lm   = lane & 15;

    // bijective XCD swizzle (192 blocks, 192 % 8 == 0)
    const int lin = blockIdx.y * 12 + blockIdx.x;
    const int s   = (lin & 7) * 24 + (lin >> 3);
    const int m0  = (s / 12) * 256;
    const int n0  = (s % 12) * 256;

    const int srow = tid >> 3;                                       // 0..63
    const int scol = (((tid & 7) ^ ((tid >> 3) & 7)) * 8);           // pre-swizzled
    const int ldst = w * 512;                                        // wave LDS base

#define STG_A(u, WBi, kq) glds16(&A[(size_t)(m0 + (u) * 64 + srow) * 1024 + (kq) + scol], \
                                 &lds[WBi][0][(u) * 4096 + ldst])
#define STG_B(u, WBi, kq) glds16(&B[(size_t)(n0 + (u) * 64 + srow) * 1024 + (kq) + scol], \
                                 &lds[WBi][1][(u) * 4096 + ldst])
#define RD_A(RBi, rrow, kk) (*(const bf16x8*)&lds[RBi][0][(rrow) * 64 + ((((kk) * 4 + quad) ^ ((rrow) & 7)) * 8)])
#define RD_B(RBi, rrow, kk) (*(const bf16x8*)&lds[RBi][1][(rrow) * 64 + ((((kk) * 4 + quad) ^ ((rrow) & 7)) * 8)])

    floatx4 acc[8][4] = {};
    bf16x8 afr[4][2];
    bf16x8 bfr[4][2];

#define MQ(MB, JB)                                                              \
  do {                                                                          \
    _Pragma("unroll")                                                           \
    for (int kk = 0; kk < 2; ++kk)                                              \
      _Pragma("unroll")                                                         \
      for (int mi = 0; mi < 4; ++mi)                                            \
        _Pragma("unroll")                                                       \
        for (int j2 = 0; j2 < 2; ++j2)                                          \
          acc[(MB) + mi][(JB) + j2] = __builtin_amdgcn_mfma_f32_16x16x32_bf16(  \
              afr[mi][kk], bfr[(JB) + j2][kk], acc[(MB) + mi][(JB) + j2], 0, 0, 0); \
  } while (0)

#define TILE(RBi, WBi, KT, LASTF)                                               \
  do {                                                                          \
    const int kn = ((KT) + 1) * 64;                                             \
    if (!(LASTF)) { STG_B(0, WBi, kn); STG_B(1, WBi, kn); }                     \
    _Pragma("unroll")                                                           \
    for (int kk = 0; kk < 2; ++kk) {                                            \
      _Pragma("unroll")                                                         \
      for (int mi = 0; mi < 4; ++mi)                                            \
        afr[mi][kk] = RD_A(RBi, wm * 128 + mi * 16 + lm, kk);                   \
      _Pragma("unroll")                                                         \
      for (int j2 = 0; j2 < 2; ++j2)                                            \
        bfr[j2][kk] = RD_B(RBi, wn * 64 + j2 * 16 + lm, kk);                    \
    }                                                                           \
    asm volatile("s_waitcnt lgkmcnt(8)" ::: "memory");                          \
    __builtin_amdgcn_s_barrier();                                               \
    asm volatile("s_waitcnt lgkmcnt(0)" ::: "memory");                          \
    __builtin_amdgcn_s_setprio(1); MQ(0, 0); __builtin_amdgcn_s_setprio(0);     \
    __builtin_amdgcn_s_barrier();                                               \
    if (!(LASTF)) { STG_B(2, WBi, kn); STG_B(3, WBi, kn); }                     \
    _Pragma("unroll")                                                           \
    for (int kk = 0; kk < 2; ++kk)                                              \
      _Pragma("unroll")                                                         \
      for (int j2 = 0; j2 < 2; ++j2)                                            \
        bfr[2 + j2][kk] = RD_B(RBi, wn * 64 + (2 + j2) * 16 + lm, kk);          \
    if (!(LASTF)) { asm volatile("s_waitcnt vmcnt(4)" ::: "memory"); }          \
    else          { asm volatile("s_waitcnt vmcnt(0)" ::: "memory"); }          \
    __builtin_amdgcn_s_barrier();                                               \
    asm volatile("s_waitcnt lgkmcnt(0)" ::: "memory");                          \
    __builtin_amdgcn_s_setprio(1); MQ(0, 2); __builtin_amdgcn_s_setprio(0);     \
    __builtin_amdgcn_s_barrier();                                               \
    if (!(LASTF)) { STG_A(0, WBi, kn); STG_A(2, WBi, kn); }                     \
    _Pragma("unroll")                                                           \
    for (int kk = 0; kk < 2; ++kk)                                              \
      _Pragma("unroll")                                                         \
      for (int mi = 0; mi < 4; ++mi)                                            \
        afr[mi][kk] = RD_A(RBi, wm * 128 + 64 + mi * 16 + lm, kk);              \
    __builtin_amdgcn_s_barrier();                                               \
    asm volatile("s_waitcnt lgkmcnt(0)" ::: "memory");                          \
    __builtin_amdgcn_s_setprio(1); MQ(4, 2); __builtin_amdgcn_s_setprio(0);     \
    __builtin_amdgcn_s_barrier();                                               \
    if (!(LASTF)) { STG_A(1, WBi, kn); STG_A(3, WBi, kn);                       \
                    asm volatile("s_waitcnt vmcnt(2)" ::: "memory"); }          \
    __builtin_amdgcn_s_barrier();                                               \
    __builtin_amdgcn_s_setprio(1); MQ(4, 0); __builtin_amdgcn_s_setprio(0);     \
    __builtin_amdgcn_s_barrier();                                               \
  } while (0)

    STG_B(0, 0, 0); STG_B(1, 0, 0); STG_B(2, 0, 0); STG_B(3, 0, 0);
    STG_A(0, 0, 0); STG_A(2, 0, 0); STG_A(1, 0, 0); STG_A(3, 0, 0);
    asm volatile("s_waitcnt vmcnt(2)" ::: "memory");
    __builtin_amdgcn_s_barrier();

    for (int kt = 0; kt < 14; kt += 2) {
        TILE(0, 1, kt, false);
        TILE(1, 0, kt + 1, false);
    }
    TILE(0, 1, 14, false);
    TILE(1, 0, 15, true);

    // -------- fused epilogue: RMSNorm + RoPE via precomputed table --------
    // q (cols < 1024) additionally scaled by 0.125*log2(e) so attention can
    // use exp2(S) directly (softmax scale folded into Q).
    const bool is_v = (n0 + wn * 64) >= 2048;   // wave-uniform; one head per wave
    if (!is_v) {
        const float qsc = ((n0 + wn * 64) < 1024) ? 0.18033688011112043f : 1.0f;
        const floatx2* rtab = (const floatx2*)ropetab;
        #pragma unroll
        for (int mi = 0; mi < 8; ++mi) {
            float rn[4];
            #pragma unroll
            for (int r = 0; r < 4; ++r) {
                float ss = 0.0f;
                #pragma unroll
                for (int j = 0; j < 4; ++j) ss += acc[mi][j][r] * acc[mi][j][r];
                ss += __shfl_xor(ss, 1, 64);
                ss += __shfl_xor(ss, 2, 64);
                ss += __shfl_xor(ss, 4, 64);
                ss += __shfl_xor(ss, 8, 64);
                rn[r] = rsqrtf(ss * (1.0f / 64.0f) + 1.1920929e-07f);
            }
            #pragma unroll
            for (int r = 0; r < 4; ++r) {
                int row = m0 + wm * 128 + mi * 16 + quad * 4 + r;
                int t = row & 2047;
                floatx2 cs0 = rtab[t * 32 + lm];        // f = lm      (j=0,2)
                floatx2 cs1 = rtab[t * 32 + 16 + lm];   // f = 16+lm   (j=1,3)
                float g = rn[r];
                #pragma unroll
                for (int j = 0; j < 4; ++j) {
                    int d = j * 16 + lm;
                    float cs = (j & 1) ? cs1[0] : cs0[0];
                    float sn = (j & 1) ? cs1[1] : cs0[1];
                    float v  = acc[mi][j][r] * g;
                    float vp = acc[mi][j ^ 2][r] * g;          // partner d^32
                    float sgn = (d < 32) ? -1.0f : 1.0f;       // (-x2, x1)
                    Cqk[(size_t)row * 2048 + (n0 + wn * 64 + d)] =
                        f2bf((v * cs + sgn * vp * sn) * qsc);
                }
            }
        }
    } else {
        #pragma unroll
        for (int mi = 0; mi < 8; ++mi)
            #pragma unroll
            for (int j = 0; j < 4; ++j) {
                int col  = n0 + wn * 64 + j * 16 + lm;
                int row0 = m0 + wm * 128 + mi * 16 + quad * 4;
                int bq = row0 >> 11, t0 = row0 & 2047;
                ushortx4 pk;
                #pragma unroll
                for (int r = 0; r < 4; ++r) pk[r] = f2bf(acc[mi][j][r]);
                *(ushortx4*)&Vt[((size_t)(bq * 1024 + (col - 2048))) * 2048 + t0] = pk;
            }
    }
#undef TILE
#undef MQ
#undef RD_A
#undef RD_B
#undef STG_A
#undef STG_B
}

// ---------------------------------------------------------------------------
// m97-structure GEMM (proj only). C[M,N] = A[M,K] @ B[N,K]^T.
// ---------------------------------------------------------------------------
template <int BN, int BK>
__global__ __launch_bounds__(256)
void gemm_bt(const unsigned short* __restrict__ A, const unsigned short* __restrict__ B,
             float* __restrict__ Cf, int M, int N, int K)
{
    constexpr int WCOLS = (BN == 128) ? 2 : 1;
    constexpr int WROWS = 4 / WCOLS;
    constexpr int MI    = 128 / (16 * WROWS);
    constexpr int LPR   = BK / 8;
    constexpr int RPI   = 64 / LPR;

    __shared__ __align__(16) unsigned short As[128 * BK];
    __shared__ __align__(16) unsigned short Bs[BN * BK];

    const int tid  = threadIdx.x;
    const int lane = tid & 63;
    const int w    = tid >> 6;
    const int wm   = w / WCOLS, wn = w % WCOLS;
    const int quad = lane >> 4;
    const int lm   = lane & 15;
    const int m0 = blockIdx.y * 128;
    const int n0 = blockIdx.x * BN;
    const int sr = lane / LPR;
    const int sc = (lane % LPR) * 8;

    floatx4 acc[MI][4] = {};

    for (int k0 = 0; k0 < K; k0 += BK) {
        __syncthreads();
        #pragma unroll
        for (int i = 0; i < 32 / RPI; ++i) {
            int r = w * 32 + i * RPI;
            glds16(&A[(size_t)(m0 + r + sr) * K + k0 + sc], &As[r * BK]);
        }
        #pragma unroll
        for (int i = 0; i < (BN / 4) / RPI; ++i) {
            int r = w * (BN / 4) + i * RPI;
            glds16(&B[(size_t)(n0 + r + sr) * K + k0 + sc], &Bs[r * BK]);
        }
        __syncthreads();

        #pragma unroll
        for (int kk = 0; kk < BK / 32; ++kk) {
            bf16x8 a[MI];
            #pragma unroll
            for (int i = 0; i < MI; ++i)
                a[i] = *(const bf16x8*)&As[(wm * (16 * MI) + i * 16 + lm) * BK + kk * 32 + quad * 8];
            #pragma unroll
            for (int j = 0; j < 4; ++j) {
                bf16x8 b = *(const bf16x8*)&Bs[(wn * 64 + j * 16 + lm) * BK + kk * 32 + quad * 8];
                #pragma unroll
                for (int i = 0; i < MI; ++i)
                    acc[i][j] = __builtin_amdgcn_mfma_f32_16x16x32_bf16(a[i], b, acc[i][j], 0, 0, 0);
            }
        }
    }

    #pragma unroll
    for (int i = 0; i < MI; ++i)
        #pragma unroll
        for (int j = 0; j < 4; ++j) {
            int col  = n0 + wn * 64 + j * 16 + lm;
            int row0 = m0 + wm * (16 * MI) + i * 16 + quad * 4;
            #pragma unroll
            for (int r = 0; r < 4; ++r)
                Cf[(size_t)(row0 + r) * N + col] = acc[i][j][r];
        }
}

// ---------------------------------------------------------------------------
// Flash attention, KEY-SPLIT waves + PREFETCH-2 / COUNTED-vmcnt (T3/T4).
// QBLK=64, 256 threads / 4 waves; wave w owns keys w*16..+15 of each 64-key
// tile (2 K-b128 + 4 V-b64 LDS reads/step). TRIPLE-buffered K/V: step t
// issues glds for tile t+2, waits vmcnt(4) (= only t+1's loads) before the
// raw s_barrier -> each load gets a full step of latency cover; never
// vmcnt(0) mid-loop. Q in regs; P in-register (mfma16 PV); o/l cross-wave
// LDS reduction once per block (its __syncthreads drains everything).
// ---------------------------------------------------------------------------
#define GRP(OT, LT, QT, g, KT, DG)                                             \
  {                                                                            \
    floatx4 sa = {};                                                           \
    sa = __builtin_amdgcn_mfma_f32_16x16x32_bf16(kf0, QT[0], sa, 0, 0, 0);     \
    sa = __builtin_amdgcn_mfma_f32_16x16x32_bf16(kf1, QT[1], sa, 0, 0, 0);     \
    float p0 = exp2f(sa[0]);                                                   \
    float p1 = exp2f(sa[1]);                                                   \
    float p2 = exp2f(sa[2]);                                                   \
    float p3 = exp2f(sa[3]);                                                   \
    if (DG) {                                                                  \
      int kb = (KT) * 64 + w * 16 + quad * 4;                                  \
      int qr = q0 + (g) * 16 + lm;                                             \
      if (kb + 0 > qr) p0 = 0.0f;                                              \
      if (kb + 1 > qr) p1 = 0.0f;                                              \
      if (kb + 2 > qr) p2 = 0.0f;                                              \
      if (kb + 3 > qr) p3 = 0.0f;                                              \
    }                                                                          \
    uintx2 pk;                                                                 \
    pk[0] = pkbf2(p0, p1);                                                     \
    pk[1] = pkbf2(p2, p3);                                                     \
    bf16x4 pa = __builtin_bit_cast(bf16x4, pk);                                \
    LT = __builtin_amdgcn_mfma_f32_16x16x16bf16_1k(pa, ones4, LT, 0, 0, 0);    \
    OT[0] = __builtin_amdgcn_mfma_f32_16x16x16bf16_1k(pa, vb0, OT[0], 0, 0, 0);\
    OT[1] = __builtin_amdgcn_mfma_f32_16x16x16bf16_1k(pa, vb1, OT[1], 0, 0, 0);\
    OT[2] = __builtin_amdgcn_mfma_f32_16x16x16bf16_1k(pa, vb2, OT[2], 0, 0, 0);\
    OT[3] = __builtin_amdgcn_mfma_f32_16x16x16bf16_1k(pa, vb3, OT[3], 0, 0, 0);\
  }

// step KT: consume (KS,VS) = buf[KT%3]; prefetch tile KT+2 into (KP,VP).
#define ATTN_STEP(KS, VS, KP, VP, KT, DG, LAST)                                \
  do {                                                                         \
    const bool pf = (KT) + 2 <= qt;                                            \
    if (pf) {                                                                  \
      const size_t tn = (size_t)((KT) + 2);                                    \
      glds16(kg + tn * 131072,         (KP) + w * 512);                        \
      glds16(kg + tn * 131072 + 65536, (KP) + 2048 + w * 512);                 \
      glds16(vg + tn * 64,             (VP) + w * 512);                        \
      glds16(vg + tn * 64 + 65536,     (VP) + 2048 + w * 512);                 \
    }                                                                          \
    bf16x8 kf0 = *(const bf16x8*)&(KS)[kfo0];                                  \
    bf16x8 kf1 = *(const bf16x8*)&(KS)[kfo1];                                  \
    bf16x4 vb0 = *(const bf16x4*)&(VS)[vbo0];                                  \
    bf16x4 vb1 = *(const bf16x4*)&(VS)[vbo1];                                  \
    bf16x4 vb2 = *(const bf16x4*)&(VS)[vbo2];                                  \
    bf16x4 vb3 = *(const bf16x4*)&(VS)[vbo3];                                  \
    GRP(oA, lA, qfA, 0, KT, DG)                                                \
    GRP(oB, lB, qfB, 1, KT, DG)                                                \
    GRP(oC, lC, qfC, 2, KT, DG)                                                \
    GRP(oD, lD, qfD, 3, KT, DG)                                                \
    if (!(LAST)) {                                                             \
      if (pf) { asm volatile("s_waitcnt vmcnt(4)" ::: "memory"); }             \
      else    { asm volatile("s_waitcnt vmcnt(0)" ::: "memory"); }             \
      __builtin_amdgcn_s_barrier();                                            \
    }                                                                          \
  } while (0)

#define OWR1(S, OT, g)                                                         \
  _Pragma("unroll")                                                            \
  for (int jd = 0; jd < 4; ++jd)                                               \
    _Pragma("unroll")                                                          \
    for (int r = 0; r < 4; ++r)                                                \
      (S)[((g) * 16 + quad * 4 + r) * 64 + jd * 16 + lm] = OT[jd][r];
#define OWR(S) { OWR1(S, oA, 0) OWR1(S, oB, 1) OWR1(S, oC, 2) OWR1(S, oD, 3) }
#define OAC1(S, OT, g)                                                         \
  _Pragma("unroll")                                                            \
  for (int jd = 0; jd < 4; ++jd)                                               \
    _Pragma("unroll")                                                          \
    for (int r = 0; r < 4; ++r)                                                \
      OT[jd][r] += (S)[((g) * 16 + quad * 4 + r) * 64 + jd * 16 + lm];
#define OAC(S) { OAC1(S, oA, 0) OAC1(S, oB, 1) OAC1(S, oC, 2) OAC1(S, oD, 3) }

#define YWR(OT, g)                                                             \
  {                                                                            \
    float rv[4];                                                               \
    _Pragma("unroll")                                                          \
    for (int r = 0; r < 4; ++r) {                                              \
      int qi = (g) * 16 + quad * 4 + r;                                        \
      rv[r] = 1.0f / (lsc[qi] + lsc[64 + qi] + lsc[128 + qi] + lsc[192 + qi]); \
    }                                                                          \
    _Pragma("unroll")                                                          \
    for (int jd = 0; jd < 4; ++jd)                                             \
      _Pragma("unroll")                                                        \
      for (int r = 0; r < 4; ++r)                                              \
        Y[((size_t)(b * 2048 + q0 + (g) * 16 + quad * 4 + r)) * 1024 +         \
          h * 64 + jd * 16 + lm] = f2bf(OT[jd][r] * rv[r]);                    \
  }

__global__ __launch_bounds__(256, 2)
void attention(const unsigned short* __restrict__ qk,
               const unsigned short* __restrict__ Vt,
               unsigned short* __restrict__ Y)
{
    // 56 KiB: QPs(8K) | Ks0..2(8K each) | Vs0..2(8K each)
    __shared__ __align__(16) unsigned short smem[28672];
    unsigned short* const QPs = smem;
    unsigned short* const Ks0 = smem + 4096;
    unsigned short* const Ks1 = smem + 8192;
    unsigned short* const Ks2 = smem + 12288;
    unsigned short* const Vs0 = smem + 16384;
    unsigned short* const Vs1 = smem + 20480;
    unsigned short* const Vs2 = smem + 24576;
    float* const lsc  = (float*)smem;            // reduction: l (1KB, over QPs)
    float* const ScrA = (float*)(smem + 4096);   // reduction: o (16KB, Ks0+Ks1)
    float* const ScrB = (float*)(smem + 16384);  // reduction: o (16KB, Vs0+Vs1)

    const int tid  = threadIdx.x;
    const int lane = tid & 63;
    const int w    = tid >> 6;           // wave = key-slice owner
    const int quad = lane >> 4;
    const int lm   = lane & 15;
    const int sx   = lm & 7;

    const int bh = blockIdx.x;
    const int qt = 31 - blockIdx.y;      // longest first
    const int b  = bh >> 4, h = bh & 15;
    const int q0 = qt * 64;
    const int NT = qt + 1;               // number of 64-key steps

    // fragment read offsets (ushort idx), XOR-swizzled chunks
    const int kfo0 = (w * 16 + lm) * 64 + ((quad)     ^ sx) * 8;
    const int kfo1 = (w * 16 + lm) * 64 + ((4 + quad) ^ sx) * 8;
    const int vch  = (w * 2 + (quad >> 1)) ^ sx;
    const int vbo0 = (0 * 16 + lm) * 64 + vch * 8 + (quad & 1) * 4;
    const int vbo1 = (1 * 16 + lm) * 64 + vch * 8 + (quad & 1) * 4;
    const int vbo2 = (2 * 16 + lm) * 64 + vch * 8 + (quad & 1) * 4;
    const int vbo3 = (3 * 16 + lm) * 64 + vch * 8 + (quad & 1) * 4;

    // staging sources (per-lane, source-col XOR so swizzled reads see orig data)
    const int srow = tid >> 3;           // 0..31 (and +32 for 2nd batch)
    const int scol = ((tid & 7) ^ (srow & 7)) * 8;
    const unsigned short* kg = qk + (size_t)b * 4194304 + 1024 + h * 64
                             + (size_t)srow * 2048 + scol;
    const unsigned short* vg = Vt + (size_t)bh * 131072 + (size_t)srow * 2048 + scol;
    const unsigned short* qg = qk + ((size_t)(b * 2048 + q0 + srow)) * 2048
                             + h * 64 + scol;

    // prologue: stage Q + tile 0 (+ tile 1 if present); counted wait.
    glds16(qg,         QPs + w * 512);
    glds16(qg + 65536, QPs + 2048 + w * 512);
    glds16(kg,         Ks0 + w * 512);
    glds16(kg + 65536, Ks0 + 2048 + w * 512);
    glds16(vg,         Vs0 + w * 512);
    glds16(vg + 65536, Vs0 + 2048 + w * 512);
    if (qt >= 1) {
        glds16(kg + 131072,         Ks1 + w * 512);
        glds16(kg + 131072 + 65536, Ks1 + 2048 + w * 512);
        glds16(vg + 64,             Vs1 + w * 512);
        glds16(vg + 64 + 65536,     Vs1 + 2048 + w * 512);
        asm volatile("s_waitcnt vmcnt(4)" ::: "memory");  // Q + tile0 done
    } else {
        asm volatile("s_waitcnt vmcnt(0)" ::: "memory");
    }
    __builtin_amdgcn_s_barrier();

    // all 4 q-group fragments in registers (read once)
    bf16x8 qfA[2], qfB[2], qfC[2], qfD[2];
    #pragma unroll
    for (int kk = 0; kk < 2; ++kk) {
        qfA[kk] = *(const bf16x8*)&QPs[(0 * 16 + lm) * 64 + ((kk * 4 + quad) ^ sx) * 8];
        qfB[kk] = *(const bf16x8*)&QPs[(1 * 16 + lm) * 64 + ((kk * 4 + quad) ^ sx) * 8];
        qfC[kk] = *(const bf16x8*)&QPs[(2 * 16 + lm) * 64 + ((kk * 4 + quad) ^ sx) * 8];
        qfD[kk] = *(const bf16x8*)&QPs[(3 * 16 + lm) * 64 + ((kk * 4 + quad) ^ sx) * 8];
    }

    bf16x4 ones4;
    #pragma unroll
    for (int i = 0; i < 4; ++i) ones4[i] = (short)0x3F80;   // bf16 1.0

    floatx4 oA[4] = {}, oB[4] = {}, oC[4] = {}, oD[4] = {};
    floatx4 lA = {}, lB = {}, lC = {}, lD = {};

    // steps 0..qt; buffer cycle of 3 (step t consumes buf t%3, prefetches
    // t+2 into buf (t+2)%3). Loop advances by 3 so the remainder always
    // starts at buffer 0. Only the final step is masked.
    int t = 0;
    for (; t + 3 < NT; t += 3) {
        ATTN_STEP(Ks0, Vs0, Ks2, Vs2, t,     false, false);
        ATTN_STEP(Ks1, Vs1, Ks0, Vs0, t + 1, false, false);
        ATTN_STEP(Ks2, Vs2, Ks1, Vs1, t + 2, false, false);
    }
    {
        const int r = NT - t;            // 1..3 remaining
        if (r == 3) {
            ATTN_STEP(Ks0, Vs0, Ks2, Vs2, t,     false, false);
            ATTN_STEP(Ks1, Vs1, Ks0, Vs0, t + 1, false, false);
            ATTN_STEP(Ks2, Vs2, Ks1, Vs1, qt,    true,  true);
        } else if (r == 2) {
            ATTN_STEP(Ks0, Vs0, Ks2, Vs2, t,  false, false);
            ATTN_STEP(Ks1, Vs1, Ks0, Vs0, qt, true,  true);
        } else {
            ATTN_STEP(Ks0, Vs0, Ks2, Vs2, qt, true, true);
        }
    }

    // ---- cross-wave o/l reduction (once per block) ----
    __syncthreads();                     // drains all counters; buffers reusable
    if (lm == 0) {
        #pragma unroll
        for (int r = 0; r < 4; ++r) {
            lsc[w * 64 +  0 + quad * 4 + r] = lA[r];
            lsc[w * 64 + 16 + quad * 4 + r] = lB[r];
            lsc[w * 64 + 32 + quad * 4 + r] = lC[r];
            lsc[w * 64 + 48 + quad * 4 + r] = lD[r];
        }
    }
    if (w == 1) { OWR(ScrA) }
    if (w == 3) { OWR(ScrB) }
    __syncthreads();
    if (w == 0) { OAC(ScrA) }
    if (w == 2) { OAC(ScrB) }
    __syncthreads();
    if (w == 2) { OWR(ScrA) }
    __syncthreads();
    if (w == 0) {
        OAC(ScrA)
        YWR(oA, 0)
        YWR(oB, 1)
        YWR(oC, 2)
        YWR(oD, 3)
    }
}

// ---------------------------------------------------------------------------
extern "C" void kernel_launch(void* const* d_in, const int* in_sizes, int n_in,
                              void* d_out, int out_size, void* d_ws, size_t ws_size,
                              hipStream_t stream)
{
    const float* x      = (const float*)d_in[0];   // [2,2048,1024] fp32
    const float* w_attn = (const float*)d_in[1];   // [3072,1024] fp32
    const float* w_proj = (const float*)d_in[2];   // [1024,1024] fp32
    float* out = (float*)d_out;                    // [2,2048,1024] fp32

    // ws: qk 16.8MB | Vt 8.4MB | y 8.4MB | wpb 2.1MB  (35.7 MB total)
    unsigned short* qkbuf = (unsigned short*)d_ws;
    unsigned short* Vtb   = qkbuf + (size_t)4096 * 2048;
    unsigned short* y     = Vtb   + (size_t)32 * 64 * 2048;
    unsigned short* wpb   = y     + (size_t)4096 * 1024;
    // d_out doubles as pre-cast scratch (dead before proj writes):
    unsigned short* xb  = (unsigned short*)d_out;             // 8.4MB
    unsigned short* wab = xb + (size_t)4096 * 1024;           // 6.3MB
    float* ropetab = (float*)(wab + (size_t)3072 * 1024);     // 512KB

    dim3 blk(256);
    cast_inputs<<<dim3(1024), blk, 0, stream>>>(x, w_attn, w_proj, xb, wab, wpb, ropetab);
    gemm_qkv_8ph<<<dim3(12, 16), dim3(512), 0, stream>>>(xb, wab, ropetab, qkbuf, Vtb);
    attention<<<dim3(32, 32), blk, 0, stream>>>(qkbuf, Vtb, y);
    gemm_bt<64, 64>
        <<<dim3(16, 32), blk, 0, stream>>>(y, wpb, out, 4096, 1024, 1024);
}